// Round 2
// baseline (287.110 us; speedup 1.0000x reference)
//
#include <hip/hip_runtime.h>
#include <stdint.h>
#include <stddef.h>

typedef unsigned short u16;
typedef unsigned int u32;
typedef float f32x4 __attribute__((ext_vector_type(4)));
typedef __bf16 bf16x8 __attribute__((ext_vector_type(8)));
typedef uint32_t u32x4 __attribute__((ext_vector_type(4)));
typedef uint32_t u32x2 __attribute__((ext_vector_type(2)));

#define DEVINL static __device__ __forceinline__

DEVINL u16 f2bf(float f) {
  union { float f; u32 u; } x; x.f = f;
  u32 r = (x.u + 0x7fffu + ((x.u >> 16) & 1u)) >> 16;
  return (u16)r;
}
DEVINL float bflo(u32 x) { union { u32 u; float f; } t; t.u = x << 16; return t.f; }
DEVINL float bfhi(u32 x) { union { u32 u; float f; } t; t.u = x & 0xffff0000u; return t.f; }

DEVINL void gl_lds16(const u16* g, u16* l) {
  __builtin_amdgcn_global_load_lds(
      (const __attribute__((address_space(1))) u32*)(const void*)g,
      (__attribute__((address_space(3))) u32*)(void*)l, 16, 0, 0);
}

DEVINL f32x4 mfma16(bf16x8 a, bf16x8 b, f32x4 c) {
  return __builtin_amdgcn_mfma_f32_16x16x32_bf16(a, b, c, 0, 0, 0);
}

// ---------------- f32 -> bf16 convert (vectorized) ----------------
__global__ void k_cvt(const float* __restrict__ src, u16* __restrict__ dst, int n4) {
  int i = blockIdx.x * 256 + threadIdx.x;
  if (i >= n4) return;
  f32x4 v = ((const f32x4*)src)[i];
  u32x2 o;
  o[0] = (u32)f2bf(v[0]) | ((u32)f2bf(v[1]) << 16);
  o[1] = (u32)f2bf(v[2]) | ((u32)f2bf(v[3]) << 16);
  ((u32x2*)dst)[i] = o;
}

// ---------------- transpose + convert: src(R x C) f32 -> dst(C x R) bf16 ----------------
__global__ void k_tcvt(const float* __restrict__ src, u16* __restrict__ dst, int R, int C) {
  __shared__ float tile[32][33];
  int tx = threadIdx.x, ty = threadIdx.y;
  int c0 = blockIdx.x * 32, r0 = blockIdx.y * 32;
#pragma unroll
  for (int j = ty; j < 32; j += 8)
    tile[j][tx] = src[(size_t)(r0 + j) * C + (c0 + tx)];
  __syncthreads();
#pragma unroll
  for (int j = ty; j < 32; j += 8)
    dst[(size_t)(c0 + j) * R + (r0 + tx)] = f2bf(tile[tx][j]);
}

// =================================================================
// 256x256 8-phase bf16 GEMM (T1+T2+T3+T4+T5), QKV only (N%256==0, K%64==0)
// C(MxN) = A(MxK) * Bt(NxK)^T + bias(3-piece), out bf16
// =================================================================
#define VMCNT_LIT(n) asm volatile("s_waitcnt vmcnt(" #n ")" ::: "memory")

template <int H, int NN, bool RDA, int VM, class ST>
DEVINL void do_phase(const u16* __restrict__ Ab, const u16* __restrict__ Bb,
                     bf16x8 (&af)[4][2], bf16x8 (&bfr)[2][2], f32x4 (&acc)[8][4],
                     int arow, int brow, int xk0e, ST&& stage) {
  if (RDA) {
#pragma unroll
    for (int m2 = 0; m2 < 4; ++m2) {
      const u16* p = Ab + (arow + H * 64 + m2 * 16) * 64;
      af[m2][0] = *(const bf16x8*)(p + xk0e);
      af[m2][1] = *(const bf16x8*)(p + (xk0e ^ 32));
    }
  }
#pragma unroll
  for (int n2 = 0; n2 < 2; ++n2) {
    const u16* p = Bb + (brow + NN * 32 + n2 * 16) * 64;
    bfr[n2][0] = *(const bf16x8*)(p + xk0e);
    bfr[n2][1] = *(const bf16x8*)(p + (xk0e ^ 32));
  }
  stage();
  if (VM >= 0) asm volatile("s_waitcnt vmcnt(%0)" :: "i"(VM < 0 ? 0 : VM) : "memory");
  __builtin_amdgcn_s_barrier();
  asm volatile("s_waitcnt lgkmcnt(0)" ::: "memory");
  __builtin_amdgcn_sched_barrier(0);
  __builtin_amdgcn_s_setprio(1);
#pragma unroll
  for (int m2 = 0; m2 < 4; ++m2)
#pragma unroll
    for (int n2 = 0; n2 < 2; ++n2)
#pragma unroll
      for (int kk = 0; kk < 2; ++kk)
        acc[H * 4 + m2][NN * 2 + n2] =
            mfma16(af[m2][kk], bfr[n2][kk], acc[H * 4 + m2][NN * 2 + n2]);
  __builtin_amdgcn_s_setprio(0);
  __builtin_amdgcn_s_barrier();
}

__global__ __launch_bounds__(512, 1) void k_gemm8(
    const u16* __restrict__ A, const u16* __restrict__ Bgl, u16* __restrict__ Cout,
    const float* __restrict__ b0, const float* __restrict__ b1, const float* __restrict__ b2,
    int M, int N, int K, int ldc, int gx)
{
  __shared__ u16 Asm[2][256 * 64];
  __shared__ u16 Bsm[2][256 * 64];

  const int nwg = gridDim.x, cpx = nwg >> 3;
  const int swz = ((int)blockIdx.x & 7) * cpx + ((int)blockIdx.x >> 3);
  const int bx = swz % gx, by = swz / gx;
  const int m0 = by * 256, n0 = bx * 256;

  const int tid = threadIdx.x;
  const int w = tid >> 6, lane = tid & 63;
  const int l15 = lane & 15, lg = lane >> 4;
  const int wr = w >> 2, wc = w & 3;

  // staging geometry: thread -> (row base, linear col16, swizzled source col)
  const int rh0 = tid >> 3, c16 = tid & 7;
  const int c16s = ((c16 ^ (rh0 & 7)) << 3);  // element offset of swizzled source col
  // frag read swizzle
  const int xk0e = ((lg ^ (l15 & 7)) << 3);
  const int arow = wr * 128 + l15;
  const int brow = wc * 64 + l15;

  const int NT = K >> 6;  // K-tiles of 64

  auto stageA = [&](int ha, int tg) {
    const int r0 = rh0 + ha * 64;  // rows {r: ((r>>6)&1)==ha}, interleaved halves
    const u16* s = A + (size_t)m0 * K + (size_t)tg * 64 + c16s;
    u16* d = Asm[tg & 1];
    gl_lds16(s + (size_t)r0 * K, d + r0 * 64 + c16 * 8);
    gl_lds16(s + (size_t)(r0 + 128) * K, d + (r0 + 128) * 64 + c16 * 8);
  };
  auto stageB = [&](int hb, int tg) {
    const int r0 = (rh0 & 31) + ((rh0 >> 5) << 6) + hb * 32;  // rows {r: ((r>>5)&1)==hb}
    const u16* s = Bgl + (size_t)n0 * K + (size_t)tg * 64 + c16s;
    u16* d = Bsm[tg & 1];
    gl_lds16(s + (size_t)r0 * K, d + r0 * 64 + c16 * 8);
    gl_lds16(s + (size_t)(r0 + 128) * K, d + (r0 + 128) * 64 + c16 * 8);
  };

  f32x4 acc[8][4] = {};
  bf16x8 af[4][2], bfr[2][2];

  // prologue: tile0 full, then A-halves of tile1 (issue order matters for vmcnt math)
  stageA(0, 0); stageA(1, 0); stageB(0, 0); stageB(1, 0);
  stageA(0, 1); stageA(1, 1);
  VMCNT_LIT(4);  // tile0 fully resident; a0(1),a1(1) may be in flight
  __builtin_amdgcn_s_barrier();

  int t = 0;
  for (; t < NT - 2; ++t) {
    const int c = t & 1;
    const u16* Ab = Asm[c]; const u16* Bb = Bsm[c];
    // P1: A-h0 + B-n0 reads | stage b0(t+1) | vmcnt(4) ensures b1(t)
    do_phase<0, 0, true, 4>(Ab, Bb, af, bfr, acc, arow, brow, xk0e,
                            [&] { stageB(0, t + 1); });
    // P2: B-n1 reads | stage a0(t+2) (region freed end P1)
    do_phase<0, 1, false, -1>(Ab, Bb, af, bfr, acc, arow, brow, xk0e,
                              [&] { stageA(0, t + 2); });
    // P3: A-h1 + B-n0 reads | stage b1(t+1)
    do_phase<1, 0, true, -1>(Ab, Bb, af, bfr, acc, arow, brow, xk0e,
                             [&] { stageB(1, t + 1); });
    // P4: B-n1 reads | stage a1(t+2) (freed end P3) | vmcnt(6) ensures b0(t+1)
    do_phase<1, 1, false, 6>(Ab, Bb, af, bfr, acc, arow, brow, xk0e,
                             [&] { stageA(1, t + 2); });
  }
  {  // t = NT-2: no a-stages (t+2 == NT); drain to 0 at P4 (conservative, exact=2)
    const int c = t & 1;
    const u16* Ab = Asm[c]; const u16* Bb = Bsm[c];
    do_phase<0, 0, true, 4>(Ab, Bb, af, bfr, acc, arow, brow, xk0e,
                            [&] { stageB(0, t + 1); });
    do_phase<0, 1, false, -1>(Ab, Bb, af, bfr, acc, arow, brow, xk0e, [&] {});
    do_phase<1, 0, true, -1>(Ab, Bb, af, bfr, acc, arow, brow, xk0e,
                             [&] { stageB(1, t + 1); });
    do_phase<1, 1, false, 0>(Ab, Bb, af, bfr, acc, arow, brow, xk0e, [&] {});
    ++t;
  }
  {  // t = NT-1: no stages; everything already drained
    const int c = t & 1;
    const u16* Ab = Asm[c]; const u16* Bb = Bsm[c];
    do_phase<0, 0, true, 0>(Ab, Bb, af, bfr, acc, arow, brow, xk0e, [&] {});
    do_phase<0, 1, false, -1>(Ab, Bb, af, bfr, acc, arow, brow, xk0e, [&] {});
    do_phase<1, 0, true, -1>(Ab, Bb, af, bfr, acc, arow, brow, xk0e, [&] {});
    do_phase<1, 1, false, -1>(Ab, Bb, af, bfr, acc, arow, brow, xk0e, [&] {});
  }

  // epilogue: bias + bf16 store
#pragma unroll
  for (int m2 = 0; m2 < 8; ++m2)
#pragma unroll
    for (int n2 = 0; n2 < 4; ++n2) {
      const int col = n0 + wc * 64 + n2 * 16 + l15;
      const float bias =
          (col < 4096) ? b0[col] : (col < 4608) ? b1[col - 4096] : b2[col - 4608];
#pragma unroll
      for (int q = 0; q < 4; ++q) {
        const int row = m0 + wr * 128 + m2 * 16 + lg * 4 + q;
        Cout[(size_t)row * ldc + col] = f2bf(acc[m2][n2][q] + bias);
      }
    }
}

// ---------------- 128x128 bf16 GEMM (out-proj): out f32, bias, N-tail, XCD swizzle ----
__global__ __launch_bounds__(256, 2) void k_gemm_o(
    const u16* __restrict__ A, const u16* __restrict__ B, float* __restrict__ Cout,
    const float* __restrict__ b0, int M, int N, int K, int ldc, int gx)
{
  __shared__ u16 Al[128 * 64];
  __shared__ u16 Bl[128 * 64];
  const int nwg = gridDim.x, cpx = nwg >> 3;
  const int swz = ((int)blockIdx.x & 7) * cpx + ((int)blockIdx.x >> 3);
  const int bx = swz % gx, by = swz / gx;

  const int tid = threadIdx.x;
  const int w = tid >> 6, lane = tid & 63;
  const int l15 = lane & 15, lg = lane >> 4;
  const int m0 = by * 128, n0 = bx * 128;
  const int wr = w >> 1, wc = w & 1;
  const int lrow = lane >> 3, lcol = lane & 7;

  f32x4 acc[4][4] = {};

  for (int kt = 0; kt < K; kt += 64) {
    if (kt) __syncthreads();
#pragma unroll
    for (int i = 0; i < 4; ++i) {
      int ar = m0 + i * 32 + w * 8 + lrow;
      gl_lds16(A + (size_t)ar * K + kt + lcol * 8, &Al[(i * 32 + w * 8) * 64]);
      int br = n0 + i * 32 + w * 8 + lrow;
      if (br >= N) br = N - 1;
      gl_lds16(B + (size_t)br * K + kt + lcol * 8, &Bl[(i * 32 + w * 8) * 64]);
    }
    __syncthreads();
#pragma unroll
    for (int ks = 0; ks < 2; ++ks) {
      bf16x8 af[4], bfr[4];
#pragma unroll
      for (int mt = 0; mt < 4; ++mt)
        af[mt] = *(const bf16x8*)&Al[(wr * 64 + mt * 16 + l15) * 64 + ks * 32 + lg * 8];
#pragma unroll
      for (int nt = 0; nt < 4; ++nt)
        bfr[nt] = *(const bf16x8*)&Bl[(wc * 64 + nt * 16 + l15) * 64 + ks * 32 + lg * 8];
#pragma unroll
      for (int mt = 0; mt < 4; ++mt)
#pragma unroll
        for (int nt = 0; nt < 4; ++nt)
          acc[mt][nt] = mfma16(af[mt], bfr[nt], acc[mt][nt]);
    }
  }

#pragma unroll
  for (int mt = 0; mt < 4; ++mt)
#pragma unroll
    for (int nt = 0; nt < 4; ++nt) {
      int col = n0 + wc * 64 + nt * 16 + l15;
      if (col >= N) continue;
      float bias = b0[col];
#pragma unroll
      for (int r = 0; r < 4; ++r) {
        int row = m0 + wr * 64 + mt * 16 + lg * 4 + r;
        Cout[(size_t)row * ldc + col] = acc[mt][nt][r] + bias;
      }
    }
}

// ---------------- in-place RoPE on QKV cols [0, 4608) ----------------
__global__ void k_rope(u16* __restrict__ qkv, const float* __restrict__ cosb,
                       const float* __restrict__ sinb) {
  int idx = blockIdx.x * 256 + threadIdx.x;  // S * 72 * 4 = 589824
  if (idx >= 2048 * 72 * 4) return;
  int oct = idx & 3;
  int h = (idx >> 2) % 72;
  int s = idx / 288;
  u16* p1 = qkv + (size_t)s * 5120 + h * 64 + oct * 8;
  u16* p2 = p1 + 32;
  const float* pc = cosb + (size_t)s * 64 + oct * 8;
  const float* ps = sinb + (size_t)s * 64 + oct * 8;
  u32x4 a = *(const u32x4*)p1;
  u32x4 b = *(const u32x4*)p2;
  f32x4 c0 = *(const f32x4*)pc, c1 = *(const f32x4*)(pc + 4);
  f32x4 s0 = *(const f32x4*)ps, s1 = *(const f32x4*)(ps + 4);
  float C[8] = {c0[0], c0[1], c0[2], c0[3], c1[0], c1[1], c1[2], c1[3]};
  float Sn[8] = {s0[0], s0[1], s0[2], s0[3], s1[0], s1[1], s1[2], s1[3]};
  u32x4 ra, rb;
#pragma unroll
  for (int i = 0; i < 4; ++i) {
    float x1l = bflo(a[i]), x1h = bfhi(a[i]);
    float x2l = bflo(b[i]), x2h = bfhi(b[i]);
    float o1l = x1l * C[2 * i] - x2l * Sn[2 * i];
    float o1h = x1h * C[2 * i + 1] - x2h * Sn[2 * i + 1];
    float o2l = x2l * C[2 * i] + x1l * Sn[2 * i];
    float o2h = x2h * C[2 * i + 1] + x1h * Sn[2 * i + 1];
    ra[i] = (u32)f2bf(o1l) | ((u32)f2bf(o1h) << 16);
    rb[i] = (u32)f2bf(o2l) | ((u32)f2bf(o2h) << 16);
  }
  *(u32x4*)p1 = ra;
  *(u32x4*)p2 = rb;
}

// ---------------- sliding-window GQA attention with sinks ----------------
__global__ __launch_bounds__(512, 1) void k_attn(
    const u16* __restrict__ qkv, const float* __restrict__ sinks, u16* __restrict__ aout)
{
  __shared__ u16 Kl[160 * 64];
  __shared__ u16 Vt[64 * 168];
  __shared__ u16 Pl[8][2][16][40];

  const int qt = blockIdx.x * 32;
  const int kv = blockIdx.y;
  const int tid = threadIdx.x;
  const int w = tid >> 6, lane = tid & 63;
  const int l15 = lane & 15, lg = lane >> 4;

  for (int idx = tid; idx < 160 * 8; idx += 512) {
    int row = idx >> 3, ch = idx & 7;
    int key = qt - 128 + row;
    u32x4 val = {0, 0, 0, 0};
    if (key >= 0) val = *(const u32x4*)(qkv + (size_t)key * 5120 + 4096 + kv * 64 + ch * 8);
    *(u32x4*)((char*)Kl + row * 128 + ((ch * 16) ^ ((row & 7) << 4))) = val;
  }
  for (int idx = tid; idx < 160 * 8; idx += 512) {
    int row = idx >> 3, ch = idx & 7;
    int key = qt - 128 + row;
    u32x4 val = {0, 0, 0, 0};
    if (key >= 0) val = *(const u32x4*)(qkv + (size_t)key * 5120 + 4608 + kv * 64 + ch * 8);
    const u16* pv16 = (const u16*)&val;
#pragma unroll
    for (int j = 0; j < 8; ++j) Vt[(ch * 8 + j) * 168 + row] = pv16[j];
  }
  __syncthreads();

  const int h = kv * 8 + w;
  const float sink = sinks[h];

  bf16x8 qf[2][2];
#pragma unroll
  for (int rt = 0; rt < 2; ++rt)
#pragma unroll
    for (int ks = 0; ks < 2; ++ks)
      qf[rt][ks] = *(const bf16x8*)(qkv + (size_t)(qt + rt * 16 + l15) * 5120 + h * 64 + ks * 32 + lg * 8);

  f32x4 S[2][5][2];
#pragma unroll
  for (int kb = 0; kb < 5; ++kb)
#pragma unroll
    for (int hh = 0; hh < 2; ++hh) {
      int krow = kb * 32 + hh * 16 + l15;
      int sw = (krow & 7) << 4;
      bf16x8 kf0 = *(const bf16x8*)((const char*)Kl + krow * 128 + ((lg * 16) ^ sw));
      bf16x8 kf1 = *(const bf16x8*)((const char*)Kl + krow * 128 + ((64 + lg * 16) ^ sw));
#pragma unroll
      for (int rt = 0; rt < 2; ++rt) {
        f32x4 a = {0.f, 0.f, 0.f, 0.f};
        a = mfma16(qf[rt][0], kf0, a);
        a = mfma16(qf[rt][1], kf1, a);
        S[rt][kb][hh] = a;
      }
    }

  float inv_s[2][4];
#pragma unroll
  for (int rt = 0; rt < 2; ++rt)
#pragma unroll
    for (int r = 0; r < 4; ++r) {
      int q_abs = qt + rt * 16 + lg * 4 + r;
      float m = -1e30f;
#pragma unroll
      for (int kb = 0; kb < 5; ++kb)
#pragma unroll
        for (int hh = 0; hh < 2; ++hh) {
          int k_abs = qt - 128 + kb * 32 + hh * 16 + l15;
          float v = S[rt][kb][hh][r] * 0.125f;
          bool ok = (k_abs >= 0) && (k_abs <= q_abs) && (q_abs - k_abs < 128);
          v = ok ? v : -1e30f;
          S[rt][kb][hh][r] = v;
          m = fmaxf(m, v);
        }
      m = fmaxf(m, __shfl_xor(m, 1, 64));
      m = fmaxf(m, __shfl_xor(m, 2, 64));
      m = fmaxf(m, __shfl_xor(m, 4, 64));
      m = fmaxf(m, __shfl_xor(m, 8, 64));
      m = fmaxf(m, sink);
      float sum = 0.f;
#pragma unroll
      for (int kb = 0; kb < 5; ++kb)
#pragma unroll
        for (int hh = 0; hh < 2; ++hh) {
          float p = __expf(S[rt][kb][hh][r] - m);
          S[rt][kb][hh][r] = p;
          sum += p;
        }
      sum += __shfl_xor(sum, 1, 64);
      sum += __shfl_xor(sum, 2, 64);
      sum += __shfl_xor(sum, 4, 64);
      sum += __shfl_xor(sum, 8, 64);
      inv_s[rt][r] = 1.0f / (sum + __expf(sink - m));
    }

  f32x4 pv[2][4] = {};
#pragma unroll
  for (int kb = 0; kb < 5; ++kb) {
    asm volatile("s_waitcnt lgkmcnt(0)" ::: "memory");
#pragma unroll
    for (int rt = 0; rt < 2; ++rt)
#pragma unroll
      for (int hh = 0; hh < 2; ++hh)
#pragma unroll
        for (int r = 0; r < 4; ++r)
          Pl[w][rt][lg * 4 + r][hh * 16 + l15] = f2bf(S[rt][kb][hh][r] * inv_s[rt][r]);
    asm volatile("s_waitcnt lgkmcnt(0)" ::: "memory");
    __builtin_amdgcn_sched_barrier(0);
    bf16x8 a0 = *(const bf16x8*)&Pl[w][0][l15][lg * 8];
    bf16x8 a1 = *(const bf16x8*)&Pl[w][1][l15][lg * 8];
#pragma unroll
    for (int nt = 0; nt < 4; ++nt) {
      bf16x8 vf = *(const bf16x8*)&Vt[(nt * 16 + l15) * 168 + kb * 32 + lg * 8];
      pv[0][nt] = mfma16(a0, vf, pv[0][nt]);
      pv[1][nt] = mfma16(a1, vf, pv[1][nt]);
    }
  }

#pragma unroll
  for (int rt = 0; rt < 2; ++rt)
#pragma unroll
    for (int nt = 0; nt < 4; ++nt)
#pragma unroll
      for (int r = 0; r < 4; ++r)
        aout[(size_t)(qt + rt * 16 + lg * 4 + r) * 4096 + h * 64 + nt * 16 + l15] =
            f2bf(pv[rt][nt][r]);
}

extern "C" void kernel_launch(void* const* d_in, const int* in_sizes, int n_in,
                              void* d_out, int out_size, void* d_ws, size_t ws_size,
                              hipStream_t stream) {
  const float* hs    = (const float*)d_in[0];
  const float* cosb  = (const float*)d_in[1];
  const float* sinb  = (const float*)d_in[2];
  const float* Wq    = (const float*)d_in[3];
  const float* bq    = (const float*)d_in[4];
  const float* Wk    = (const float*)d_in[5];
  const float* bk    = (const float*)d_in[6];
  const float* Wv    = (const float*)d_in[7];
  const float* bv    = (const float*)d_in[8];
  const float* Wo    = (const float*)d_in[9];
  const float* bo    = (const float*)d_in[10];
  const float* sinks = (const float*)d_in[11];

  char* ws = (char*)d_ws;
  u16* hsb   = (u16*)ws;  ws += (size_t)2048 * 2880 * 2;
  u16* WqkvT = (u16*)ws;  ws += (size_t)5120 * 2880 * 2;
  u16* WoT   = (u16*)ws;  ws += (size_t)2880 * 4096 * 2;
  u16* QKV   = (u16*)ws;  ws += (size_t)2048 * 5120 * 2;
  u16* AOut  = (u16*)ws;  ws += (size_t)2048 * 4096 * 2;

  dim3 tblk(32, 8);
  k_cvt<<<5760, 256, 0, stream>>>(hs, hsb, 1474560);
  k_tcvt<<<dim3(4096 / 32, 2880 / 32), tblk, 0, stream>>>(Wq, WqkvT, 2880, 4096);
  k_tcvt<<<dim3(512 / 32, 2880 / 32), tblk, 0, stream>>>(Wk, WqkvT + (size_t)4096 * 2880, 2880, 512);
  k_tcvt<<<dim3(512 / 32, 2880 / 32), tblk, 0, stream>>>(Wv, WqkvT + (size_t)4608 * 2880, 2880, 512);
  k_tcvt<<<dim3(2880 / 32, 4096 / 32), tblk, 0, stream>>>(Wo, WoT, 4096, 2880);

  // QKV: 256x256 8-phase, grid 8x20 = 160 (nwg % 8 == 0)
  k_gemm8<<<160, 512, 0, stream>>>(hsb, WqkvT, QKV, bq, bk, bv, 2048, 5120, 2880, 5120, 20);

  k_rope<<<2304, 256, 0, stream>>>(QKV, cosb, sinb);

  k_attn<<<dim3(64, 8), 512, 0, stream>>>(QKV, sinks, AOut);

  // out-proj: 128x128 with XCD swizzle, grid 23*16 = 368 (368 % 8 == 0)
  k_gemm_o<<<368, 256, 0, stream>>>(AOut, WoT, (float*)d_out, bo, 2048, 2880, 4096, 2880, 23);
}

// Round 3
// 240.643 us; speedup vs baseline: 1.1931x; 1.1931x over previous
//
#include <hip/hip_runtime.h>
#include <stdint.h>
#include <stddef.h>

typedef unsigned short u16;
typedef unsigned int u32;
typedef float f32x4 __attribute__((ext_vector_type(4)));
typedef __bf16 bf16x8 __attribute__((ext_vector_type(8)));
typedef uint32_t u32x4 __attribute__((ext_vector_type(4)));
typedef uint32_t u32x2 __attribute__((ext_vector_type(2)));

#define DEVINL static __device__ __forceinline__

DEVINL u16 f2bf(float f) {
  union { float f; u32 u; } x; x.f = f;
  u32 r = (x.u + 0x7fffu + ((x.u >> 16) & 1u)) >> 16;
  return (u16)r;
}
DEVINL float bflo(u32 x) { union { u32 u; float f; } t; t.u = x << 16; return t.f; }
DEVINL float bfhi(u32 x) { union { u32 u; float f; } t; t.u = x & 0xffff0000u; return t.f; }

DEVINL void gl_lds16(const u16* g, u16* l) {
  __builtin_amdgcn_global_load_lds(
      (const __attribute__((address_space(1))) u32*)(const void*)g,
      (__attribute__((address_space(3))) u32*)(void*)l, 16, 0, 0);
}

DEVINL f32x4 mfma16(bf16x8 a, bf16x8 b, f32x4 c) {
  return __builtin_amdgcn_mfma_f32_16x16x32_bf16(a, b, c, 0, 0, 0);
}

// ---------------- f32 -> bf16 convert (vectorized) ----------------
__global__ void k_cvt(const float* __restrict__ src, u16* __restrict__ dst, int n4) {
  int i = blockIdx.x * 256 + threadIdx.x;
  if (i >= n4) return;
  f32x4 v = ((const f32x4*)src)[i];
  u32x2 o;
  o[0] = (u32)f2bf(v[0]) | ((u32)f2bf(v[1]) << 16);
  o[1] = (u32)f2bf(v[2]) | ((u32)f2bf(v[3]) << 16);
  ((u32x2*)dst)[i] = o;
}

// ---------------- transpose + convert: src(R x C) f32 -> dst(C x R) bf16 ----------------
__global__ void k_tcvt(const float* __restrict__ src, u16* __restrict__ dst, int R, int C) {
  __shared__ float tile[32][33];
  int tx = threadIdx.x, ty = threadIdx.y;
  int c0 = blockIdx.x * 32, r0 = blockIdx.y * 32;
#pragma unroll
  for (int j = ty; j < 32; j += 8)
    tile[j][tx] = src[(size_t)(r0 + j) * C + (c0 + tx)];
  __syncthreads();
#pragma unroll
  for (int j = ty; j < 32; j += 8)
    dst[(size_t)(c0 + j) * R + (r0 + tx)] = f2bf(tile[tx][j]);
}

// =================================================================
// QKV GEMM: 256M x 160N tiles -> 8 x 32 = 256 blocks (100% CU fill)
// 8 waves = 4M x 2N, wave owns 64x80 (4x5 frags). 4 phases/K-tile.
// A double-buffered, B triple-buffered; single vmcnt(5)/K-tile at P4.
// =================================================================
__global__ __launch_bounds__(512, 1) void k_gemmq(
    const u16* __restrict__ A, const u16* __restrict__ Bgl, u16* __restrict__ Cout,
    const float* __restrict__ pb0, const float* __restrict__ pb1, const float* __restrict__ pb2)
{
  constexpr int K = 2880, NT = 45, LDC = 5120;
  __shared__ u16 Asm[2][256 * 64];
  __shared__ u16 Bsm[3][160 * 64];

  const int bid = blockIdx.x;
  const int swz = (bid & 7) * 32 + (bid >> 3);   // 256 % 8 == 0, bijective
  const int bx = swz & 31, by = swz >> 5;
  const int m0 = by * 256, n0 = bx * 160;

  const int tid = threadIdx.x;
  const int w = tid >> 6, lane = tid & 63;
  const int l15 = lane & 15, lg = lane >> 4;
  const int wr = w >> 1, wc = w & 1;

  const u16* Ag = A + (size_t)m0 * K;
  const u16* Bg = Bgl + (size_t)n0 * K;

  auto stA = [&](int tg, int half) {   // 2 loads/thread; half 0: rows 0-127, 1: 128-255
    u16* d = Asm[tg & 1];
    const u16* s = Ag + tg * 64;
#pragma unroll
    for (int r = 0; r < 2; ++r) {
      int slot = tid + half * 1024 + r * 512;
      int row = slot >> 3, c = slot & 7;
      gl_lds16(s + (size_t)row * K + ((c ^ (row & 7)) << 3), d + row * 64 + c * 8);
    }
  };
  auto stB01 = [&](int tg, int buf) {  // 2 loads/thread; rows 0-127
    u16* d = Bsm[buf];
    const u16* s = Bg + tg * 64;
#pragma unroll
    for (int r = 0; r < 2; ++r) {
      int slot = tid + r * 512;
      int row = slot >> 3, c = slot & 7;
      gl_lds16(s + (size_t)row * K + ((c ^ (row & 7)) << 3), d + row * 64 + c * 8);
    }
  };
  auto stB2 = [&](int tg, int buf) {   // 1 load/thread; rows 128-159 (upper half dup-writes)
    u16* d = Bsm[buf];
    const u16* s = Bg + tg * 64;
    int slot = 1024 + (tid & 255);
    int row = slot >> 3, c = slot & 7;
    gl_lds16(s + (size_t)row * K + ((c ^ (row & 7)) << 3), d + row * 64 + c * 8);
  };

  const int ra = wr * 64 + l15;
  const int rb = wc * 80 + l15;
  const int x0 = (lg ^ (l15 & 7)) << 3;
  const int x1 = x0 ^ 32;

  f32x4 acc[4][5] = {};

  auto iter = [&](int t, int bc, int b2, bool d2, bool d1, bool drain) {
    const u16* Ab = Asm[t & 1];
    const u16* Bb = Bsm[bc];
    bf16x8 af[2][2], bfr[5][2];
    // ---- P1: read A m01 + B n01 (8 reads); stage sA1(t+1)
#pragma unroll
    for (int m = 0; m < 2; ++m) {
      af[m][0] = *(const bf16x8*)&Ab[(ra + m * 16) * 64 + x0];
      af[m][1] = *(const bf16x8*)&Ab[(ra + m * 16) * 64 + x1];
    }
#pragma unroll
    for (int n = 0; n < 2; ++n) {
      bfr[n][0] = *(const bf16x8*)&Bb[(rb + n * 16) * 64 + x0];
      bfr[n][1] = *(const bf16x8*)&Bb[(rb + n * 16) * 64 + x1];
    }
    if (d1) stA(t + 1, 1);
    __builtin_amdgcn_s_barrier();
    asm volatile("s_waitcnt lgkmcnt(0)" ::: "memory");
    __builtin_amdgcn_s_setprio(1);
#pragma unroll
    for (int kk = 0; kk < 2; ++kk)
#pragma unroll
      for (int m = 0; m < 2; ++m)
#pragma unroll
        for (int n = 0; n < 2; ++n)
          acc[m][n] = mfma16(af[m][kk], bfr[n][kk], acc[m][n]);
    __builtin_amdgcn_s_setprio(0);
    __builtin_amdgcn_s_barrier();
    // ---- P2: read B n234 (6 reads)
#pragma unroll
    for (int n = 2; n < 5; ++n) {
      bfr[n][0] = *(const bf16x8*)&Bb[(rb + n * 16) * 64 + x0];
      bfr[n][1] = *(const bf16x8*)&Bb[(rb + n * 16) * 64 + x1];
    }
    __builtin_amdgcn_s_barrier();
    asm volatile("s_waitcnt lgkmcnt(0)" ::: "memory");
    __builtin_amdgcn_s_setprio(1);
#pragma unroll
    for (int kk = 0; kk < 2; ++kk)
#pragma unroll
      for (int m = 0; m < 2; ++m)
#pragma unroll
        for (int n = 2; n < 5; ++n)
          acc[m][n] = mfma16(af[m][kk], bfr[n][kk], acc[m][n]);
    __builtin_amdgcn_s_setprio(0);
    __builtin_amdgcn_s_barrier();
    // ---- P3: read A m23 (4 reads, overwrite af); stage sB01(t+2)
#pragma unroll
    for (int m = 0; m < 2; ++m) {
      af[m][0] = *(const bf16x8*)&Ab[(ra + 32 + m * 16) * 64 + x0];
      af[m][1] = *(const bf16x8*)&Ab[(ra + 32 + m * 16) * 64 + x1];
    }
    if (d2) stB01(t + 2, b2);
    __builtin_amdgcn_s_barrier();
    asm volatile("s_waitcnt lgkmcnt(0)" ::: "memory");
    __builtin_amdgcn_s_setprio(1);
#pragma unroll
    for (int kk = 0; kk < 2; ++kk)
#pragma unroll
      for (int m = 0; m < 2; ++m)
#pragma unroll
        for (int n = 0; n < 2; ++n)
          acc[2 + m][n] = mfma16(af[m][kk], bfr[n][kk], acc[2 + m][n]);
    __builtin_amdgcn_s_setprio(0);
    __builtin_amdgcn_s_barrier();
    // ---- P4: stage sB2(t+2)+sA0(t+2); counted wait
    if (d2) { stB2(t + 2, b2); stA(t + 2, 0); }
    if (drain) { asm volatile("s_waitcnt vmcnt(0)" ::: "memory"); }
    else       { asm volatile("s_waitcnt vmcnt(5)" ::: "memory"); }
    __builtin_amdgcn_s_barrier();
    __builtin_amdgcn_s_setprio(1);
#pragma unroll
    for (int kk = 0; kk < 2; ++kk)
#pragma unroll
      for (int m = 0; m < 2; ++m)
#pragma unroll
        for (int n = 2; n < 5; ++n)
          acc[2 + m][n] = mfma16(af[m][kk], bfr[n][kk], acc[2 + m][n]);
    __builtin_amdgcn_s_setprio(0);
    __builtin_amdgcn_s_barrier();
  };

  // prologue: tile0 (7 loads), then tile1 B + A0 (5 loads)
  stA(0, 0); stA(0, 1); stB01(0, 0); stB2(0, 0);
  __builtin_amdgcn_sched_barrier(0);
  stB01(1, 1); stB2(1, 1); stA(1, 0);
  asm volatile("s_waitcnt vmcnt(5)" ::: "memory");
  __builtin_amdgcn_s_barrier();

  int bc = 0, b2 = 2;
  int t = 0;
  for (; t < NT - 2; ++t) {
    iter(t, bc, b2, true, true, false);
    bc = bc == 2 ? 0 : bc + 1;
    b2 = b2 == 2 ? 0 : b2 + 1;
  }
  iter(NT - 2, bc, b2, false, true, true);
  bc = bc == 2 ? 0 : bc + 1;
  b2 = b2 == 2 ? 0 : b2 + 1;
  iter(NT - 1, bc, b2, false, false, true);

  // epilogue: bias + bf16 store
#pragma unroll
  for (int m2 = 0; m2 < 4; ++m2)
#pragma unroll
    for (int n = 0; n < 5; ++n) {
      int col = n0 + wc * 80 + n * 16 + l15;
      float bias = (col < 4096) ? pb0[col] : (col < 4608) ? pb1[col - 4096] : pb2[col - 4608];
#pragma unroll
      for (int q = 0; q < 4; ++q) {
        int row = m0 + wr * 64 + m2 * 16 + lg * 4 + q;
        Cout[(size_t)row * LDC + col] = f2bf(acc[m2][n][q] + bias);
      }
    }
}

// =================================================================
// Out-proj GEMM: 256M x 96N tiles -> 8 x 30 = 240 blocks (94% fill)
// 8 waves = 4M x 2N, wave owns 64x48 (4x3 frags). 2 phases/K-tile.
// A and B triple-buffered; stages all at P1; vmcnt(6) at P2.
// =================================================================
__global__ __launch_bounds__(512, 1) void k_gemmo(
    const u16* __restrict__ A, const u16* __restrict__ Bgl, float* __restrict__ Cout,
    const float* __restrict__ pb0)
{
  constexpr int K = 4096, NT = 64, LDC = 2880;
  __shared__ u16 Asm[3][256 * 64];
  __shared__ u16 Bsm[3][96 * 64];

  const int bid = blockIdx.x;
  const int swz = (bid & 7) * 30 + (bid >> 3);   // 240 % 8 == 0, bijective
  const int bx = swz % 30, by = swz / 30;
  const int m0 = by * 256, n0 = bx * 96;

  const int tid = threadIdx.x;
  const int w = tid >> 6, lane = tid & 63;
  const int l15 = lane & 15, lg = lane >> 4;
  const int wr = w >> 1, wc = w & 1;

  const u16* Ag = A + (size_t)m0 * K;
  const u16* Bg = Bgl + (size_t)n0 * K;

  auto stA = [&](int tg, int half, int buf) {
    u16* d = Asm[buf];
    const u16* s = Ag + tg * 64;
#pragma unroll
    for (int r = 0; r < 2; ++r) {
      int slot = tid + half * 1024 + r * 512;
      int row = slot >> 3, c = slot & 7;
      gl_lds16(s + (size_t)row * K + ((c ^ (row & 7)) << 3), d + row * 64 + c * 8);
    }
  };
  auto stB = [&](int tg, int buf) {    // 2 loads/thread; 768 slots (upper dup-writes)
    u16* d = Bsm[buf];
    const u16* s = Bg + tg * 64;
    {
      int slot = tid;
      int row = slot >> 3, c = slot & 7;
      gl_lds16(s + (size_t)row * K + ((c ^ (row & 7)) << 3), d + row * 64 + c * 8);
    }
    {
      int slot = 512 + (tid & 255);
      int row = slot >> 3, c = slot & 7;
      gl_lds16(s + (size_t)row * K + ((c ^ (row & 7)) << 3), d + row * 64 + c * 8);
    }
  };

  const int ra = wr * 64 + l15;
  const int rb = wc * 48 + l15;
  const int x0 = (lg ^ (l15 & 7)) << 3;
  const int x1 = x0 ^ 32;

  f32x4 acc[4][3] = {};

  auto iter = [&](int t, int ac, int a2, bool d2, bool drain) {
    const u16* Ab = Asm[ac];
    const u16* Bb = Bsm[ac];
    bf16x8 af[2][2], bfr[3][2];
    // ---- P1: read A m01 (4) + B n012 (6); stage all of tile t+2 (6 loads)
#pragma unroll
    for (int m = 0; m < 2; ++m) {
      af[m][0] = *(const bf16x8*)&Ab[(ra + m * 16) * 64 + x0];
      af[m][1] = *(const bf16x8*)&Ab[(ra + m * 16) * 64 + x1];
    }
#pragma unroll
    for (int n = 0; n < 3; ++n) {
      bfr[n][0] = *(const bf16x8*)&Bb[(rb + n * 16) * 64 + x0];
      bfr[n][1] = *(const bf16x8*)&Bb[(rb + n * 16) * 64 + x1];
    }
    if (d2) { stA(t + 2, 0, a2); stA(t + 2, 1, a2); stB(t + 2, a2); }
    __builtin_amdgcn_s_barrier();
    asm volatile("s_waitcnt lgkmcnt(0)" ::: "memory");
    __builtin_amdgcn_s_setprio(1);
#pragma unroll
    for (int kk = 0; kk < 2; ++kk)
#pragma unroll
      for (int m = 0; m < 2; ++m)
#pragma unroll
        for (int n = 0; n < 3; ++n)
          acc[m][n] = mfma16(af[m][kk], bfr[n][kk], acc[m][n]);
    __builtin_amdgcn_s_setprio(0);
    __builtin_amdgcn_s_barrier();
    // ---- P2: read A m23 (4); counted wait
#pragma unroll
    for (int m = 0; m < 2; ++m) {
      af[m][0] = *(const bf16x8*)&Ab[(ra + 32 + m * 16) * 64 + x0];
      af[m][1] = *(const bf16x8*)&Ab[(ra + 32 + m * 16) * 64 + x1];
    }
    if (drain) { asm volatile("s_waitcnt vmcnt(0)" ::: "memory"); }
    else       { asm volatile("s_waitcnt vmcnt(6)" ::: "memory"); }
    __builtin_amdgcn_s_barrier();
    asm volatile("s_waitcnt lgkmcnt(0)" ::: "memory");
    __builtin_amdgcn_s_setprio(1);
#pragma unroll
    for (int kk = 0; kk < 2; ++kk)
#pragma unroll
      for (int m = 0; m < 2; ++m)
#pragma unroll
        for (int n = 0; n < 3; ++n)
          acc[2 + m][n] = mfma16(af[m][kk], bfr[n][kk], acc[2 + m][n]);
    __builtin_amdgcn_s_setprio(0);
    __builtin_amdgcn_s_barrier();
  };

  // prologue: tile0 then tile1 (6 + 6 loads)
  stA(0, 0, 0); stA(0, 1, 0); stB(0, 0);
  __builtin_amdgcn_sched_barrier(0);
  stA(1, 0, 1); stA(1, 1, 1); stB(1, 1);
  asm volatile("s_waitcnt vmcnt(6)" ::: "memory");
  __builtin_amdgcn_s_barrier();

  int ac = 0, a2 = 2;
  int t = 0;
  for (; t < NT - 2; ++t) {
    iter(t, ac, a2, true, false);
    ac = ac == 2 ? 0 : ac + 1;
    a2 = a2 == 2 ? 0 : a2 + 1;
  }
  iter(NT - 2, ac, a2, false, true);
  ac = ac == 2 ? 0 : ac + 1;
  a2 = a2 == 2 ? 0 : a2 + 1;
  iter(NT - 1, ac, a2, false, true);

#pragma unroll
  for (int m2 = 0; m2 < 4; ++m2)
#pragma unroll
    for (int n = 0; n < 3; ++n) {
      int col = n0 + wc * 48 + n * 16 + l15;
      float bias = pb0[col];
#pragma unroll
      for (int q = 0; q < 4; ++q) {
        int row = m0 + wr * 64 + m2 * 16 + lg * 4 + q;
        Cout[(size_t)row * LDC + col] = acc[m2][n][q] + bias;
      }
    }
}

// ---------------- in-place RoPE on QKV cols [0, 4608) ----------------
__global__ void k_rope(u16* __restrict__ qkv, const float* __restrict__ cosb,
                       const float* __restrict__ sinb) {
  int idx = blockIdx.x * 256 + threadIdx.x;  // S * 72 * 4 = 589824
  if (idx >= 2048 * 72 * 4) return;
  int oct = idx & 3;
  int h = (idx >> 2) % 72;
  int s = idx / 288;
  u16* p1 = qkv + (size_t)s * 5120 + h * 64 + oct * 8;
  u16* p2 = p1 + 32;
  const float* pc = cosb + (size_t)s * 64 + oct * 8;
  const float* ps = sinb + (size_t)s * 64 + oct * 8;
  u32x4 a = *(const u32x4*)p1;
  u32x4 b = *(const u32x4*)p2;
  f32x4 c0 = *(const f32x4*)pc, c1 = *(const f32x4*)(pc + 4);
  f32x4 s0 = *(const f32x4*)ps, s1 = *(const f32x4*)(ps + 4);
  float C[8] = {c0[0], c0[1], c0[2], c0[3], c1[0], c1[1], c1[2], c1[3]};
  float Sn[8] = {s0[0], s0[1], s0[2], s0[3], s1[0], s1[1], s1[2], s1[3]};
  u32x4 ra, rb;
#pragma unroll
  for (int i = 0; i < 4; ++i) {
    float x1l = bflo(a[i]), x1h = bfhi(a[i]);
    float x2l = bflo(b[i]), x2h = bfhi(b[i]);
    float o1l = x1l * C[2 * i] - x2l * Sn[2 * i];
    float o1h = x1h * C[2 * i + 1] - x2h * Sn[2 * i + 1];
    float o2l = x2l * C[2 * i] + x1l * Sn[2 * i];
    float o2h = x2h * C[2 * i + 1] + x1h * Sn[2 * i + 1];
    ra[i] = (u32)f2bf(o1l) | ((u32)f2bf(o1h) << 16);
    rb[i] = (u32)f2bf(o2l) | ((u32)f2bf(o2h) << 16);
  }
  *(u32x4*)p1 = ra;
  *(u32x4*)p2 = rb;
}

// ---------------- sliding-window GQA attention with sinks ----------------
__global__ __launch_bounds__(512, 1) void k_attn(
    const u16* __restrict__ qkv, const float* __restrict__ sinks, u16* __restrict__ aout)
{
  __shared__ u16 Kl[160 * 64];
  __shared__ u16 Vt[64 * 168];
  __shared__ u16 Pl[8][2][16][40];

  const int qt = blockIdx.x * 32;
  const int kv = blockIdx.y;
  const int tid = threadIdx.x;
  const int w = tid >> 6, lane = tid & 63;
  const int l15 = lane & 15, lg = lane >> 4;

  for (int idx = tid; idx < 160 * 8; idx += 512) {
    int row = idx >> 3, ch = idx & 7;
    int key = qt - 128 + row;
    u32x4 val = {0, 0, 0, 0};
    if (key >= 0) val = *(const u32x4*)(qkv + (size_t)key * 5120 + 4096 + kv * 64 + ch * 8);
    *(u32x4*)((char*)Kl + row * 128 + ((ch * 16) ^ ((row & 7) << 4))) = val;
  }
  for (int idx = tid; idx < 160 * 8; idx += 512) {
    int row = idx >> 3, ch = idx & 7;
    int key = qt - 128 + row;
    u32x4 val = {0, 0, 0, 0};
    if (key >= 0) val = *(const u32x4*)(qkv + (size_t)key * 5120 + 4608 + kv * 64 + ch * 8);
    const u16* pv16 = (const u16*)&val;
#pragma unroll
    for (int j = 0; j < 8; ++j) Vt[(ch * 8 + j) * 168 + row] = pv16[j];
  }
  __syncthreads();

  const int h = kv * 8 + w;
  const float sink = sinks[h];

  bf16x8 qf[2][2];
#pragma unroll
  for (int rt = 0; rt < 2; ++rt)
#pragma unroll
    for (int ks = 0; ks < 2; ++ks)
      qf[rt][ks] = *(const bf16x8*)(qkv + (size_t)(qt + rt * 16 + l15) * 5120 + h * 64 + ks * 32 + lg * 8);

  f32x4 S[2][5][2];
#pragma unroll
  for (int kb = 0; kb < 5; ++kb)
#pragma unroll
    for (int hh = 0; hh < 2; ++hh) {
      int krow = kb * 32 + hh * 16 + l15;
      int sw = (krow & 7) << 4;
      bf16x8 kf0 = *(const bf16x8*)((const char*)Kl + krow * 128 + ((lg * 16) ^ sw));
      bf16x8 kf1 = *(const bf16x8*)((const char*)Kl + krow * 128 + ((64 + lg * 16) ^ sw));
#pragma unroll
      for (int rt = 0; rt < 2; ++rt) {
        f32x4 a = {0.f, 0.f, 0.f, 0.f};
        a = mfma16(qf[rt][0], kf0, a);
        a = mfma16(qf[rt][1], kf1, a);
        S[rt][kb][hh] = a;
      }
    }

  float inv_s[2][4];
#pragma unroll
  for (int rt = 0; rt < 2; ++rt)
#pragma unroll
    for (int r = 0; r < 4; ++r) {
      int q_abs = qt + rt * 16 + lg * 4 + r;
      float m = -1e30f;
#pragma unroll
      for (int kb = 0; kb < 5; ++kb)
#pragma unroll
        for (int hh = 0; hh < 2; ++hh) {
          int k_abs = qt - 128 + kb * 32 + hh * 16 + l15;
          float v = S[rt][kb][hh][r] * 0.125f;
          bool ok = (k_abs >= 0) && (k_abs <= q_abs) && (q_abs - k_abs < 128);
          v = ok ? v : -1e30f;
          S[rt][kb][hh][r] = v;
          m = fmaxf(m, v);
        }
      m = fmaxf(m, __shfl_xor(m, 1, 64));
      m = fmaxf(m, __shfl_xor(m, 2, 64));
      m = fmaxf(m, __shfl_xor(m, 4, 64));
      m = fmaxf(m, __shfl_xor(m, 8, 64));
      m = fmaxf(m, sink);
      float sum = 0.f;
#pragma unroll
      for (int kb = 0; kb < 5; ++kb)
#pragma unroll
        for (int hh = 0; hh < 2; ++hh) {
          float p = __expf(S[rt][kb][hh][r] - m);
          S[rt][kb][hh][r] = p;
          sum += p;
        }
      sum += __shfl_xor(sum, 1, 64);
      sum += __shfl_xor(sum, 2, 64);
      sum += __shfl_xor(sum, 4, 64);
      sum += __shfl_xor(sum, 8, 64);
      inv_s[rt][r] = 1.0f / (sum + __expf(sink - m));
    }

  f32x4 pv[2][4] = {};
#pragma unroll
  for (int kb = 0; kb < 5; ++kb) {
    asm volatile("s_waitcnt lgkmcnt(0)" ::: "memory");
#pragma unroll
    for (int rt = 0; rt < 2; ++rt)
#pragma unroll
      for (int hh = 0; hh < 2; ++hh)
#pragma unroll
        for (int r = 0; r < 4; ++r)
          Pl[w][rt][lg * 4 + r][hh * 16 + l15] = f2bf(S[rt][kb][hh][r] * inv_s[rt][r]);
    asm volatile("s_waitcnt lgkmcnt(0)" ::: "memory");
    __builtin_amdgcn_sched_barrier(0);
    bf16x8 a0 = *(const bf16x8*)&Pl[w][0][l15][lg * 8];
    bf16x8 a1 = *(const bf16x8*)&Pl[w][1][l15][lg * 8];
#pragma unroll
    for (int nt = 0; nt < 4; ++nt) {
      bf16x8 vf = *(const bf16x8*)&Vt[(nt * 16 + l15) * 168 + kb * 32 + lg * 8];
      pv[0][nt] = mfma16(a0, vf, pv[0][nt]);
      pv[1][nt] = mfma16(a1, vf, pv[1][nt]);
    }
  }

#pragma unroll
  for (int rt = 0; rt < 2; ++rt)
#pragma unroll
    for (int nt = 0; nt < 4; ++nt)
#pragma unroll
      for (int r = 0; r < 4; ++r)
        aout[(size_t)(qt + rt * 16 + lg * 4 + r) * 4096 + h * 64 + nt * 16 + l15] =
            f2bf(pv[rt][nt][r]);
}

extern "C" void kernel_launch(void* const* d_in, const int* in_sizes, int n_in,
                              void* d_out, int out_size, void* d_ws, size_t ws_size,
                              hipStream_t stream) {
  const float* hs    = (const float*)d_in[0];
  const float* cosb  = (const float*)d_in[1];
  const float* sinb  = (const float*)d_in[2];
  const float* Wq    = (const float*)d_in[3];
  const float* bq    = (const float*)d_in[4];
  const float* Wk    = (const float*)d_in[5];
  const float* bk    = (const float*)d_in[6];
  const float* Wv    = (const float*)d_in[7];
  const float* bv    = (const float*)d_in[8];
  const float* Wo    = (const float*)d_in[9];
  const float* bo    = (const float*)d_in[10];
  const float* sinks = (const float*)d_in[11];

  char* ws = (char*)d_ws;
  u16* hsb   = (u16*)ws;  ws += (size_t)2048 * 2880 * 2;
  u16* WqkvT = (u16*)ws;  ws += (size_t)5120 * 2880 * 2;
  u16* WoT   = (u16*)ws;  ws += (size_t)2880 * 4096 * 2;
  u16* QKV   = (u16*)ws;  ws += (size_t)2048 * 5120 * 2;
  u16* AOut  = (u16*)ws;  ws += (size_t)2048 * 4096 * 2;

  dim3 tblk(32, 8);
  k_cvt<<<5760, 256, 0, stream>>>(hs, hsb, 1474560);
  k_tcvt<<<dim3(4096 / 32, 2880 / 32), tblk, 0, stream>>>(Wq, WqkvT, 2880, 4096);
  k_tcvt<<<dim3(512 / 32, 2880 / 32), tblk, 0, stream>>>(Wk, WqkvT + (size_t)4096 * 2880, 2880, 512);
  k_tcvt<<<dim3(512 / 32, 2880 / 32), tblk, 0, stream>>>(Wv, WqkvT + (size_t)4608 * 2880, 2880, 512);
  k_tcvt<<<dim3(2880 / 32, 4096 / 32), tblk, 0, stream>>>(Wo, WoT, 4096, 2880);

  k_gemmq<<<256, 512, 0, stream>>>(hsb, WqkvT, QKV, bq, bk, bv);

  k_rope<<<2304, 256, 0, stream>>>(QKV, cosb, sinb);

  k_attn<<<dim3(64, 8), 512, 0, stream>>>(QKV, sinks, AOut);

  k_gemmo<<<240, 512, 0, stream>>>(AOut, WoT, (float*)d_out, bo);
}

// Round 4
// 196.507 us; speedup vs baseline: 1.4611x; 1.2246x over previous
//
#include <hip/hip_runtime.h>
#include <stdint.h>
#include <stddef.h>

typedef unsigned short u16;
typedef unsigned int u32;
typedef float f32x4 __attribute__((ext_vector_type(4)));
typedef __bf16 bf16x8 __attribute__((ext_vector_type(8)));
typedef uint32_t u32x4 __attribute__((ext_vector_type(4)));
typedef uint32_t u32x2 __attribute__((ext_vector_type(2)));

#define DEVINL static __device__ __forceinline__
#define VMW(n) asm volatile("s_waitcnt vmcnt(" #n ")" ::: "memory")
#define LGK0() asm volatile("s_waitcnt lgkmcnt(0)" ::: "memory")
#define SB0() __builtin_amdgcn_sched_barrier(0)

DEVINL u16 f2bf(float f) {
  union { float f; u32 u; } x; x.f = f;
  u32 r = (x.u + 0x7fffu + ((x.u >> 16) & 1u)) >> 16;
  return (u16)r;
}
DEVINL float bflo(u32 x) { union { u32 u; float f; } t; t.u = x << 16; return t.f; }
DEVINL float bfhi(u32 x) { union { u32 u; float f; } t; t.u = x & 0xffff0000u; return t.f; }

DEVINL void gl_lds16(const u16* g, u16* l) {
  __builtin_amdgcn_global_load_lds(
      (const __attribute__((address_space(1))) u32*)(const void*)g,
      (__attribute__((address_space(3))) u32*)(void*)l, 16, 0, 0);
}

DEVINL f32x4 mfma16(bf16x8 a, bf16x8 b, f32x4 c) {
  return __builtin_amdgcn_mfma_f32_16x16x32_bf16(a, b, c, 0, 0, 0);
}

// ---------------- f32 -> bf16 convert (vectorized) ----------------
__global__ void k_cvt(const float* __restrict__ src, u16* __restrict__ dst, int n4) {
  int i = blockIdx.x * 256 + threadIdx.x;
  if (i >= n4) return;
  f32x4 v = ((const f32x4*)src)[i];
  u32x2 o;
  o[0] = (u32)f2bf(v[0]) | ((u32)f2bf(v[1]) << 16);
  o[1] = (u32)f2bf(v[2]) | ((u32)f2bf(v[3]) << 16);
  ((u32x2*)dst)[i] = o;
}

// ---------------- transpose + convert: src(R x C) f32 -> dst(C x R) bf16 ----------------
__global__ void k_tcvt(const float* __restrict__ src, u16* __restrict__ dst, int R, int C) {
  __shared__ float tile[32][33];
  int tx = threadIdx.x, ty = threadIdx.y;
  int c0 = blockIdx.x * 32, r0 = blockIdx.y * 32;
#pragma unroll
  for (int j = ty; j < 32; j += 8)
    tile[j][tx] = src[(size_t)(r0 + j) * C + (c0 + tx)];
  __syncthreads();
#pragma unroll
  for (int j = ty; j < 32; j += 8)
    dst[(size_t)(c0 + j) * R + (r0 + tx)] = f2bf(tile[tx][j]);
}

// =================================================================
// QKV GEMM: 128M x 160N tiles -> grid 16x32 = 512 blocks (2 blocks/CU)
// 4 waves = 2M x 2N, wave owns 64x80 (4x5 frags). 4 phases, 2 barriers/K-tile.
// A,B double-buffered; counted vmcnt: VM(5)@P2-end, VM(2)@P4-end.
// =================================================================
__global__ __launch_bounds__(256, 2) void k_gemmq(
    const u16* __restrict__ A, const u16* __restrict__ Bgl, u16* __restrict__ Cout,
    const float* __restrict__ pb0, const float* __restrict__ pb1, const float* __restrict__ pb2)
{
  constexpr int K = 2880, NT = 45, LDC = 5120;
  __shared__ u16 Asm[2][128 * 64];
  __shared__ u16 Bsm[2][160 * 64];

  const int bid = blockIdx.x;
  const int swz = (bid & 7) * 64 + (bid >> 3);   // 512 % 8 == 0, bijective
  const int bx = swz >> 4, by = swz & 15;        // same-XCD blocks share bx (B panels in L2)
  const int m0 = by * 128, n0 = bx * 160;

  const int tid = threadIdx.x;
  const int w = tid >> 6, lane = tid & 63;
  const int l15 = lane & 15, lg = lane >> 4;
  const int wr = w >> 1, wc = w & 1;

  const u16* Ag = A + (size_t)m0 * K;
  const u16* Bg = Bgl + (size_t)n0 * K;

  auto ld1 = [&](const u16* s, u16* d, int slot) {
    int row = slot >> 3, c = slot & 7;
    gl_lds16(s + (size_t)row * K + ((c ^ (row & 7)) << 3), d + row * 64 + c * 8);
  };
  // A part0: rows {0-31, 64-95} (read at P1); part1: rows {32-63, 96-127} (read at P3)
  auto stApart = [&](int tg, int part) {
    u16* d = Asm[tg & 1];
    const u16* s = Ag + tg * 64;
    ld1(s, d, part * 256 + tid);
    ld1(s, d, part * 256 + 512 + tid);
  };
  // B a-set: rows {0-31, 80-111} (read at P1); b-set: rows {32-79, 112-159} (read at P2)
  auto stBa = [&](int tg) {
    u16* d = Bsm[tg & 1];
    const u16* s = Bg + tg * 64;
    ld1(s, d, tid);
    ld1(s, d, 640 + tid);
  };
  auto stBb = [&](int tg) {
    u16* d = Bsm[tg & 1];
    const u16* s = Bg + tg * 64;
    ld1(s, d, 256 + tid);
    ld1(s, d, (tid < 128) ? (512 + tid) : (768 + tid));
    ld1(s, d, 1024 + tid);
  };

  const int ra = wr * 64 + l15;
  const int rb = wc * 80 + l15;
  const int x0 = (lg ^ (l15 & 7)) << 3;
  const int x1 = x0 ^ 32;

  f32x4 acc[4][5] = {};
  bf16x8 af[2][2], bfr[5][2];

  // prologue: tile0 fully staged; VM(2) leaves Ap2(0) outstanding (forced at t0 P2-end)
  stBa(0); stBb(0); stApart(0, 0); stApart(0, 1);
  VMW(2);
  __builtin_amdgcn_s_barrier();
  SB0();

  for (int t = 0; t < NT; ++t) {
    const u16* Ab = Asm[t & 1];
    const u16* Bb_ = Bsm[t & 1];
    const bool st = (t + 1 < NT);
    // ---- P1: read A m01 + B n01; stage Ba(t+1)
#pragma unroll
    for (int m = 0; m < 2; ++m) {
      af[m][0] = *(const bf16x8*)&Ab[(ra + m * 16) * 64 + x0];
      af[m][1] = *(const bf16x8*)&Ab[(ra + m * 16) * 64 + x1];
    }
#pragma unroll
    for (int n = 0; n < 2; ++n) {
      bfr[n][0] = *(const bf16x8*)&Bb_[(rb + n * 16) * 64 + x0];
      bfr[n][1] = *(const bf16x8*)&Bb_[(rb + n * 16) * 64 + x1];
    }
    if (st) stBa(t + 1);
    LGK0(); SB0();
    __builtin_amdgcn_s_setprio(1);
#pragma unroll
    for (int kk = 0; kk < 2; ++kk)
#pragma unroll
      for (int m = 0; m < 2; ++m)
#pragma unroll
        for (int n = 0; n < 2; ++n)
          acc[m][n] = mfma16(af[m][kk], bfr[n][kk], acc[m][n]);
    __builtin_amdgcn_s_setprio(0);
    // ---- P2: read B n234; stage Bb(t+1); VM(5) forces Ap2(t); barrier
#pragma unroll
    for (int n = 2; n < 5; ++n) {
      bfr[n][0] = *(const bf16x8*)&Bb_[(rb + n * 16) * 64 + x0];
      bfr[n][1] = *(const bf16x8*)&Bb_[(rb + n * 16) * 64 + x1];
    }
    if (st) stBb(t + 1);
    LGK0(); SB0();
    __builtin_amdgcn_s_setprio(1);
#pragma unroll
    for (int kk = 0; kk < 2; ++kk)
#pragma unroll
      for (int m = 0; m < 2; ++m)
#pragma unroll
        for (int n = 2; n < 5; ++n)
          acc[m][n] = mfma16(af[m][kk], bfr[n][kk], acc[m][n]);
    __builtin_amdgcn_s_setprio(0);
    if (st) { VMW(5); } else { VMW(0); }
    __builtin_amdgcn_s_barrier();
    SB0();
    // ---- P3: read A m23; stage Ap1(t+1)
#pragma unroll
    for (int m = 0; m < 2; ++m) {
      af[m][0] = *(const bf16x8*)&Ab[(ra + 32 + m * 16) * 64 + x0];
      af[m][1] = *(const bf16x8*)&Ab[(ra + 32 + m * 16) * 64 + x1];
    }
    if (st) stApart(t + 1, 0);
    LGK0(); SB0();
    __builtin_amdgcn_s_setprio(1);
#pragma unroll
    for (int kk = 0; kk < 2; ++kk)
#pragma unroll
      for (int m = 0; m < 2; ++m)
#pragma unroll
        for (int n = 0; n < 2; ++n)
          acc[2 + m][n] = mfma16(af[m][kk], bfr[n][kk], acc[2 + m][n]);
    __builtin_amdgcn_s_setprio(0);
    // ---- P4: stage Ap2(t+1); VM(2) forces Ba/Bb/Ap1(t+1); barrier
    if (st) stApart(t + 1, 1);
    __builtin_amdgcn_s_setprio(1);
#pragma unroll
    for (int kk = 0; kk < 2; ++kk)
#pragma unroll
      for (int m = 0; m < 2; ++m)
#pragma unroll
        for (int n = 2; n < 5; ++n)
          acc[2 + m][n] = mfma16(af[m][kk], bfr[n][kk], acc[2 + m][n]);
    __builtin_amdgcn_s_setprio(0);
    VMW(2);
    __builtin_amdgcn_s_barrier();
    SB0();
  }

  // epilogue: bias + bf16 store
#pragma unroll
  for (int m2 = 0; m2 < 4; ++m2)
#pragma unroll
    for (int n = 0; n < 5; ++n) {
      int col = n0 + wc * 80 + n * 16 + l15;
      float bias = (col < 4096) ? pb0[col] : (col < 4608) ? pb1[col - 4096] : pb2[col - 4608];
#pragma unroll
      for (int q = 0; q < 4; ++q) {
        int row = m0 + wr * 64 + m2 * 16 + lg * 4 + q;
        Cout[(size_t)row * LDC + col] = f2bf(acc[m2][n][q] + bias);
      }
    }
}

// =================================================================
// Out-proj GEMM: 128M x 96N tiles -> grid 16x30 = 480 blocks (~2/CU)
// 4 waves = 2M x 2N, wave owns 64x48 (4x3 frags). 2 phases, 2 barriers/K-tile.
// =================================================================
__global__ __launch_bounds__(256, 2) void k_gemmo(
    const u16* __restrict__ A, const u16* __restrict__ Bgl, float* __restrict__ Cout,
    const float* __restrict__ pb0)
{
  constexpr int K = 4096, NT = 64, LDC = 2880;
  __shared__ u16 Asm[2][128 * 64];
  __shared__ u16 Bsm[2][96 * 64];

  const int bid = blockIdx.x;
  const int swz = (bid & 7) * 60 + (bid >> 3);   // 480 % 8 == 0, bijective
  const int bx = swz / 16, by = swz & 15;
  const int m0 = by * 128, n0 = bx * 96;

  const int tid = threadIdx.x;
  const int w = tid >> 6, lane = tid & 63;
  const int l15 = lane & 15, lg = lane >> 4;
  const int wr = w >> 1, wc = w & 1;

  const u16* Ag = A + (size_t)m0 * K;
  const u16* Bg = Bgl + (size_t)n0 * K;

  auto ld1 = [&](const u16* s, u16* d, int slot) {
    int row = slot >> 3, c = slot & 7;
    gl_lds16(s + (size_t)row * K + ((c ^ (row & 7)) << 3), d + row * 64 + c * 8);
  };
  auto stApart = [&](int tg, int part) {
    u16* d = Asm[tg & 1];
    const u16* s = Ag + tg * 64;
    ld1(s, d, part * 256 + tid);
    ld1(s, d, part * 256 + 512 + tid);
  };
  auto stB = [&](int tg) {   // 96 rows = 768 slots
    u16* d = Bsm[tg & 1];
    const u16* s = Bg + tg * 64;
    ld1(s, d, tid);
    ld1(s, d, 256 + tid);
    ld1(s, d, 512 + tid);
  };

  const int ra = wr * 64 + l15;
  const int rb = wc * 48 + l15;
  const int x0 = (lg ^ (l15 & 7)) << 3;
  const int x1 = x0 ^ 32;

  f32x4 acc[4][3] = {};
  bf16x8 af[2][2], bfr[3][2];

  // prologue: tile0 staged; VM(2) leaves Ap2(0)
  stB(0); stApart(0, 0); stApart(0, 1);
  VMW(2);
  __builtin_amdgcn_s_barrier();
  SB0();

  for (int t = 0; t < NT; ++t) {
    const u16* Ab = Asm[t & 1];
    const u16* Bb_ = Bsm[t & 1];
    const bool st = (t + 1 < NT);
    // ---- P1: read A m01 + B n012; stage B(t+1) + Ap1(t+1); VM(5) forces Ap2(t)
#pragma unroll
    for (int m = 0; m < 2; ++m) {
      af[m][0] = *(const bf16x8*)&Ab[(ra + m * 16) * 64 + x0];
      af[m][1] = *(const bf16x8*)&Ab[(ra + m * 16) * 64 + x1];
    }
#pragma unroll
    for (int n = 0; n < 3; ++n) {
      bfr[n][0] = *(const bf16x8*)&Bb_[(rb + n * 16) * 64 + x0];
      bfr[n][1] = *(const bf16x8*)&Bb_[(rb + n * 16) * 64 + x1];
    }
    if (st) { stB(t + 1); stApart(t + 1, 0); }
    LGK0(); SB0();
    __builtin_amdgcn_s_setprio(1);
#pragma unroll
    for (int kk = 0; kk < 2; ++kk)
#pragma unroll
      for (int m = 0; m < 2; ++m)
#pragma unroll
        for (int n = 0; n < 3; ++n)
          acc[m][n] = mfma16(af[m][kk], bfr[n][kk], acc[m][n]);
    __builtin_amdgcn_s_setprio(0);
    if (st) { VMW(5); } else { VMW(0); }
    __builtin_amdgcn_s_barrier();
    SB0();
    // ---- P2: read A m23; stage Ap2(t+1); VM(2) forces B(t+1)+Ap1(t+1)
#pragma unroll
    for (int m = 0; m < 2; ++m) {
      af[m][0] = *(const bf16x8*)&Ab[(ra + 32 + m * 16) * 64 + x0];
      af[m][1] = *(const bf16x8*)&Ab[(ra + 32 + m * 16) * 64 + x1];
    }
    if (st) stApart(t + 1, 1);
    LGK0(); SB0();
    __builtin_amdgcn_s_setprio(1);
#pragma unroll
    for (int kk = 0; kk < 2; ++kk)
#pragma unroll
      for (int m = 0; m < 2; ++m)
#pragma unroll
        for (int n = 0; n < 3; ++n)
          acc[2 + m][n] = mfma16(af[m][kk], bfr[n][kk], acc[2 + m][n]);
    __builtin_amdgcn_s_setprio(0);
    VMW(2);
    __builtin_amdgcn_s_barrier();
    SB0();
  }

#pragma unroll
  for (int m2 = 0; m2 < 4; ++m2)
#pragma unroll
    for (int n = 0; n < 3; ++n) {
      int col = n0 + wc * 48 + n * 16 + l15;
      float bias = pb0[col];
#pragma unroll
      for (int q = 0; q < 4; ++q) {
        int row = m0 + wr * 64 + m2 * 16 + lg * 4 + q;
        Cout[(size_t)row * LDC + col] = acc[m2][n][q] + bias;
      }
    }
}

// ---------------- in-place RoPE on QKV cols [0, 4608) ----------------
__global__ void k_rope(u16* __restrict__ qkv, const float* __restrict__ cosb,
                       const float* __restrict__ sinb) {
  int idx = blockIdx.x * 256 + threadIdx.x;  // S * 72 * 4 = 589824
  if (idx >= 2048 * 72 * 4) return;
  int oct = idx & 3;
  int h = (idx >> 2) % 72;
  int s = idx / 288;
  u16* p1 = qkv + (size_t)s * 5120 + h * 64 + oct * 8;
  u16* p2 = p1 + 32;
  const float* pc = cosb + (size_t)s * 64 + oct * 8;
  const float* ps = sinb + (size_t)s * 64 + oct * 8;
  u32x4 a = *(const u32x4*)p1;
  u32x4 b = *(const u32x4*)p2;
  f32x4 c0 = *(const f32x4*)pc, c1 = *(const f32x4*)(pc + 4);
  f32x4 s0 = *(const f32x4*)ps, s1 = *(const f32x4*)(ps + 4);
  float C[8] = {c0[0], c0[1], c0[2], c0[3], c1[0], c1[1], c1[2], c1[3]};
  float Sn[8] = {s0[0], s0[1], s0[2], s0[3], s1[0], s1[1], s1[2], s1[3]};
  u32x4 ra, rb;
#pragma unroll
  for (int i = 0; i < 4; ++i) {
    float x1l = bflo(a[i]), x1h = bfhi(a[i]);
    float x2l = bflo(b[i]), x2h = bfhi(b[i]);
    float o1l = x1l * C[2 * i] - x2l * Sn[2 * i];
    float o1h = x1h * C[2 * i + 1] - x2h * Sn[2 * i + 1];
    float o2l = x2l * C[2 * i] + x1l * Sn[2 * i];
    float o2h = x2h * C[2 * i + 1] + x1h * Sn[2 * i + 1];
    ra[i] = (u32)f2bf(o1l) | ((u32)f2bf(o1h) << 16);
    rb[i] = (u32)f2bf(o2l) | ((u32)f2bf(o2h) << 16);
  }
  *(u32x4*)p1 = ra;
  *(u32x4*)p2 = rb;
}

// ---------------- sliding-window GQA attention with sinks ----------------
__global__ __launch_bounds__(512, 1) void k_attn(
    const u16* __restrict__ qkv, const float* __restrict__ sinks, u16* __restrict__ aout)
{
  __shared__ u16 Kl[160 * 64];
  __shared__ u16 Vt[64 * 168];
  __shared__ u16 Pl[8][2][16][40];

  const int qt = blockIdx.x * 32;
  const int kv = blockIdx.y;
  const int tid = threadIdx.x;
  const int w = tid >> 6, lane = tid & 63;
  const int l15 = lane & 15, lg = lane >> 4;

  for (int idx = tid; idx < 160 * 8; idx += 512) {
    int row = idx >> 3, ch = idx & 7;
    int key = qt - 128 + row;
    u32x4 val = {0, 0, 0, 0};
    if (key >= 0) val = *(const u32x4*)(qkv + (size_t)key * 5120 + 4096 + kv * 64 + ch * 8);
    *(u32x4*)((char*)Kl + row * 128 + ((ch * 16) ^ ((row & 7) << 4))) = val;
  }
  for (int idx = tid; idx < 160 * 8; idx += 512) {
    int row = idx >> 3, ch = idx & 7;
    int key = qt - 128 + row;
    u32x4 val = {0, 0, 0, 0};
    if (key >= 0) val = *(const u32x4*)(qkv + (size_t)key * 5120 + 4608 + kv * 64 + ch * 8);
    const u16* pv16 = (const u16*)&val;
#pragma unroll
    for (int j = 0; j < 8; ++j) Vt[(ch * 8 + j) * 168 + row] = pv16[j];
  }
  __syncthreads();

  const int h = kv * 8 + w;
  const float sink = sinks[h];

  bf16x8 qf[2][2];
#pragma unroll
  for (int rt = 0; rt < 2; ++rt)
#pragma unroll
    for (int ks = 0; ks < 2; ++ks)
      qf[rt][ks] = *(const bf16x8*)(qkv + (size_t)(qt + rt * 16 + l15) * 5120 + h * 64 + ks * 32 + lg * 8);

  f32x4 S[2][5][2];
#pragma unroll
  for (int kb = 0; kb < 5; ++kb)
#pragma unroll
    for (int hh = 0; hh < 2; ++hh) {
      int krow = kb * 32 + hh * 16 + l15;
      int sw = (krow & 7) << 4;
      bf16x8 kf0 = *(const bf16x8*)((const char*)Kl + krow * 128 + ((lg * 16) ^ sw));
      bf16x8 kf1 = *(const bf16x8*)((const char*)Kl + krow * 128 + ((64 + lg * 16) ^ sw));
#pragma unroll
      for (int rt = 0; rt < 2; ++rt) {
        f32x4 a = {0.f, 0.f, 0.f, 0.f};
        a = mfma16(qf[rt][0], kf0, a);
        a = mfma16(qf[rt][1], kf1, a);
        S[rt][kb][hh] = a;
      }
    }

  float inv_s[2][4];
#pragma unroll
  for (int rt = 0; rt < 2; ++rt)
#pragma unroll
    for (int r = 0; r < 4; ++r) {
      int q_abs = qt + rt * 16 + lg * 4 + r;
      float m = -1e30f;
#pragma unroll
      for (int kb = 0; kb < 5; ++kb)
#pragma unroll
        for (int hh = 0; hh < 2; ++hh) {
          int k_abs = qt - 128 + kb * 32 + hh * 16 + l15;
          float v = S[rt][kb][hh][r] * 0.125f;
          bool ok = (k_abs >= 0) && (k_abs <= q_abs) && (q_abs - k_abs < 128);
          v = ok ? v : -1e30f;
          S[rt][kb][hh][r] = v;
          m = fmaxf(m, v);
        }
      m = fmaxf(m, __shfl_xor(m, 1, 64));
      m = fmaxf(m, __shfl_xor(m, 2, 64));
      m = fmaxf(m, __shfl_xor(m, 4, 64));
      m = fmaxf(m, __shfl_xor(m, 8, 64));
      m = fmaxf(m, sink);
      float sum = 0.f;
#pragma unroll
      for (int kb = 0; kb < 5; ++kb)
#pragma unroll
        for (int hh = 0; hh < 2; ++hh) {
          float p = __expf(S[rt][kb][hh][r] - m);
          S[rt][kb][hh][r] = p;
          sum += p;
        }
      sum += __shfl_xor(sum, 1, 64);
      sum += __shfl_xor(sum, 2, 64);
      sum += __shfl_xor(sum, 4, 64);
      sum += __shfl_xor(sum, 8, 64);
      inv_s[rt][r] = 1.0f / (sum + __expf(sink - m));
    }

  f32x4 pv[2][4] = {};
#pragma unroll
  for (int kb = 0; kb < 5; ++kb) {
    asm volatile("s_waitcnt lgkmcnt(0)" ::: "memory");
#pragma unroll
    for (int rt = 0; rt < 2; ++rt)
#pragma unroll
      for (int hh = 0; hh < 2; ++hh)
#pragma unroll
        for (int r = 0; r < 4; ++r)
          Pl[w][rt][lg * 4 + r][hh * 16 + l15] = f2bf(S[rt][kb][hh][r] * inv_s[rt][r]);
    asm volatile("s_waitcnt lgkmcnt(0)" ::: "memory");
    __builtin_amdgcn_sched_barrier(0);
    bf16x8 a0 = *(const bf16x8*)&Pl[w][0][l15][lg * 8];
    bf16x8 a1 = *(const bf16x8*)&Pl[w][1][l15][lg * 8];
#pragma unroll
    for (int nt = 0; nt < 4; ++nt) {
      bf16x8 vf = *(const bf16x8*)&Vt[(nt * 16 + l15) * 168 + kb * 32 + lg * 8];
      pv[0][nt] = mfma16(a0, vf, pv[0][nt]);
      pv[1][nt] = mfma16(a1, vf, pv[1][nt]);
    }
  }

#pragma unroll
  for (int rt = 0; rt < 2; ++rt)
#pragma unroll
    for (int nt = 0; nt < 4; ++nt)
#pragma unroll
      for (int r = 0; r < 4; ++r)
        aout[(size_t)(qt + rt * 16 + lg * 4 + r) * 4096 + h * 64 + nt * 16 + l15] =
            f2bf(pv[rt][nt][r]);
}

extern "C" void kernel_launch(void* const* d_in, const int* in_sizes, int n_in,
                              void* d_out, int out_size, void* d_ws, size_t ws_size,
                              hipStream_t stream) {
  const float* hs    = (const float*)d_in[0];
  const float* cosb  = (const float*)d_in[1];
  const float* sinb  = (const float*)d_in[2];
  const float* Wq    = (const float*)d_in[3];
  const float* bq    = (const float*)d_in[4];
  const float* Wk    = (const float*)d_in[5];
  const float* bk    = (const float*)d_in[6];
  const float* Wv    = (const float*)d_in[7];
  const float* bv    = (const float*)d_in[8];
  const float* Wo    = (const float*)d_in[9];
  const float* bo    = (const float*)d_in[10];
  const float* sinks = (const float*)d_in[11];

  char* ws = (char*)d_ws;
  u16* hsb   = (u16*)ws;  ws += (size_t)2048 * 2880 * 2;
  u16* WqkvT = (u16*)ws;  ws += (size_t)5120 * 2880 * 2;
  u16* WoT   = (u16*)ws;  ws += (size_t)2880 * 4096 * 2;
  u16* QKV   = (u16*)ws;  ws += (size_t)2048 * 5120 * 2;
  u16* AOut  = (u16*)ws;  ws += (size_t)2048 * 4096 * 2;

  dim3 tblk(32, 8);
  k_cvt<<<5760, 256, 0, stream>>>(hs, hsb, 1474560);
  k_tcvt<<<dim3(4096 / 32, 2880 / 32), tblk, 0, stream>>>(Wq, WqkvT, 2880, 4096);
  k_tcvt<<<dim3(512 / 32, 2880 / 32), tblk, 0, stream>>>(Wk, WqkvT + (size_t)4096 * 2880, 2880, 512);
  k_tcvt<<<dim3(512 / 32, 2880 / 32), tblk, 0, stream>>>(Wv, WqkvT + (size_t)4608 * 2880, 2880, 512);
  k_tcvt<<<dim3(2880 / 32, 4096 / 32), tblk, 0, stream>>>(Wo, WoT, 4096, 2880);

  k_gemmq<<<512, 256, 0, stream>>>(hsb, WqkvT, QKV, bq, bk, bv);

  k_rope<<<2304, 256, 0, stream>>>(QKV, cosb, sinb);

  k_attn<<<dim3(64, 8), 512, 0, stream>>>(QKV, sinks, AOut);

  k_gemmo<<<480, 256, 0, stream>>>(AOut, WoT, (float*)d_out, bo);
}

// Round 5
// 182.218 us; speedup vs baseline: 1.5756x; 1.0784x over previous
//
#include <hip/hip_runtime.h>
#include <stdint.h>
#include <stddef.h>

typedef unsigned short u16;
typedef unsigned int u32;
typedef float f32x4 __attribute__((ext_vector_type(4)));
typedef __bf16 bf16x8 __attribute__((ext_vector_type(8)));
typedef uint32_t u32x4 __attribute__((ext_vector_type(4)));
typedef uint32_t u32x2 __attribute__((ext_vector_type(2)));

#define DEVINL static __device__ __forceinline__
#define VMW(n) asm volatile("s_waitcnt vmcnt(" #n ")" ::: "memory")
#define LGK0() asm volatile("s_waitcnt lgkmcnt(0)" ::: "memory")
#define SB0() __builtin_amdgcn_sched_barrier(0)

DEVINL u16 f2bf(float f) {
  union { float f; u32 u; } x; x.f = f;
  u32 r = (x.u + 0x7fffu + ((x.u >> 16) & 1u)) >> 16;
  return (u16)r;
}
DEVINL float bflo(u32 x) { union { u32 u; float f; } t; t.u = x << 16; return t.f; }
DEVINL float bfhi(u32 x) { union { u32 u; float f; } t; t.u = x & 0xffff0000u; return t.f; }

DEVINL void gl_lds16(const u16* g, u16* l) {
  __builtin_amdgcn_global_load_lds(
      (const __attribute__((address_space(1))) u32*)(const void*)g,
      (__attribute__((address_space(3))) u32*)(void*)l, 16, 0, 0);
}

DEVINL f32x4 mfma16(bf16x8 a, bf16x8 b, f32x4 c) {
  return __builtin_amdgcn_mfma_f32_16x16x32_bf16(a, b, c, 0, 0, 0);
}

// ---------------- f32 -> bf16 convert (vectorized) ----------------
__global__ void k_cvt(const float* __restrict__ src, u16* __restrict__ dst, int n4) {
  int i = blockIdx.x * 256 + threadIdx.x;
  if (i >= n4) return;
  f32x4 v = ((const f32x4*)src)[i];
  u32x2 o;
  o[0] = (u32)f2bf(v[0]) | ((u32)f2bf(v[1]) << 16);
  o[1] = (u32)f2bf(v[2]) | ((u32)f2bf(v[3]) << 16);
  ((u32x2*)dst)[i] = o;
}

// ------- transpose + convert, 64x64 tiles, 16B stores: src(R x C) f32 -> dst(C x R) bf16
__global__ __launch_bounds__(256) void k_tcvt2(const float* __restrict__ src,
                                               u16* __restrict__ dst, int R, int C) {
  __shared__ float t[64][65];
  const int tid = threadIdx.x;
  const int r0 = blockIdx.y * 64, c0 = blockIdx.x * 64;
  // load: thread -> row rr = tid>>2, 16 cols at (tid&3)*16; f32x4 loads, scalar LDS writes
  {
    const int rr = tid >> 2, cg = (tid & 3) * 16;
    const float* s = src + (size_t)(r0 + rr) * C + c0 + cg;
#pragma unroll
    for (int i = 0; i < 4; ++i) {
      f32x4 v = *(const f32x4*)(s + 4 * i);
      t[rr][cg + 4 * i + 0] = v[0];
      t[rr][cg + 4 * i + 1] = v[1];
      t[rr][cg + 4 * i + 2] = v[2];
      t[rr][cg + 4 * i + 3] = v[3];
    }
  }
  __syncthreads();
  // store: thread -> rg = tid&7 (8 consecutive r), c = (tid>>3) + 32*iter; 16B stores
  {
    const int rg = tid & 7, cb = tid >> 3;
#pragma unroll
    for (int it = 0; it < 2; ++it) {
      const int c = cb + it * 32;
      float v[8];
#pragma unroll
      for (int i = 0; i < 8; ++i) v[i] = t[rg * 8 + i][c];
      u32x4 o;
#pragma unroll
      for (int j = 0; j < 4; ++j)
        o[j] = (u32)f2bf(v[2 * j]) | ((u32)f2bf(v[2 * j + 1]) << 16);
      *(u32x4*)(dst + (size_t)(c0 + c) * R + r0 + rg * 8) = o;
    }
  }
}

// =================================================================
// QKV GEMM: 128M x 160N tiles -> grid 16x32 = 512 blocks (2 blocks/CU)
// 4 waves = 2M x 2N, wave owns 64x80 (4x5 frags). 4 phases, 2 barriers/K-tile.
// A,B double-buffered; counted vmcnt: VM(5)@P2-end, VM(2)@P4-end.
// =================================================================
__global__ __launch_bounds__(256, 2) void k_gemmq(
    const u16* __restrict__ A, const u16* __restrict__ Bgl, u16* __restrict__ Cout,
    const float* __restrict__ pb0, const float* __restrict__ pb1, const float* __restrict__ pb2)
{
  constexpr int K = 2880, NT = 45, LDC = 5120;
  __shared__ u16 Asm[2][128 * 64];
  __shared__ u16 Bsm[2][160 * 64];

  const int bid = blockIdx.x;
  const int swz = (bid & 7) * 64 + (bid >> 3);   // 512 % 8 == 0, bijective
  const int bx = swz >> 4, by = swz & 15;        // same-XCD blocks share bx (B panels in L2)
  const int m0 = by * 128, n0 = bx * 160;

  const int tid = threadIdx.x;
  const int w = tid >> 6, lane = tid & 63;
  const int l15 = lane & 15, lg = lane >> 4;
  const int wr = w >> 1, wc = w & 1;

  const u16* Ag = A + (size_t)m0 * K;
  const u16* Bg = Bgl + (size_t)n0 * K;

  auto ld1 = [&](const u16* s, u16* d, int slot) {
    int row = slot >> 3, c = slot & 7;
    gl_lds16(s + (size_t)row * K + ((c ^ (row & 7)) << 3), d + row * 64 + c * 8);
  };
  auto stApart = [&](int tg, int part) {
    u16* d = Asm[tg & 1];
    const u16* s = Ag + tg * 64;
    ld1(s, d, part * 256 + tid);
    ld1(s, d, part * 256 + 512 + tid);
  };
  auto stBa = [&](int tg) {
    u16* d = Bsm[tg & 1];
    const u16* s = Bg + tg * 64;
    ld1(s, d, tid);
    ld1(s, d, 640 + tid);
  };
  auto stBb = [&](int tg) {
    u16* d = Bsm[tg & 1];
    const u16* s = Bg + tg * 64;
    ld1(s, d, 256 + tid);
    ld1(s, d, (tid < 128) ? (512 + tid) : (768 + tid));
    ld1(s, d, 1024 + tid);
  };

  const int ra = wr * 64 + l15;
  const int rb = wc * 80 + l15;
  const int x0 = (lg ^ (l15 & 7)) << 3;
  const int x1 = x0 ^ 32;

  f32x4 acc[4][5] = {};
  bf16x8 af[2][2], bfr[5][2];

  stBa(0); stBb(0); stApart(0, 0); stApart(0, 1);
  VMW(2);
  __builtin_amdgcn_s_barrier();
  SB0();

  for (int t = 0; t < NT; ++t) {
    const u16* Ab = Asm[t & 1];
    const u16* Bb_ = Bsm[t & 1];
    const bool st = (t + 1 < NT);
    // ---- P1: read A m01 + B n01; stage Ba(t+1)
#pragma unroll
    for (int m = 0; m < 2; ++m) {
      af[m][0] = *(const bf16x8*)&Ab[(ra + m * 16) * 64 + x0];
      af[m][1] = *(const bf16x8*)&Ab[(ra + m * 16) * 64 + x1];
    }
#pragma unroll
    for (int n = 0; n < 2; ++n) {
      bfr[n][0] = *(const bf16x8*)&Bb_[(rb + n * 16) * 64 + x0];
      bfr[n][1] = *(const bf16x8*)&Bb_[(rb + n * 16) * 64 + x1];
    }
    if (st) stBa(t + 1);
    LGK0(); SB0();
    __builtin_amdgcn_s_setprio(1);
#pragma unroll
    for (int kk = 0; kk < 2; ++kk)
#pragma unroll
      for (int m = 0; m < 2; ++m)
#pragma unroll
        for (int n = 0; n < 2; ++n)
          acc[m][n] = mfma16(af[m][kk], bfr[n][kk], acc[m][n]);
    __builtin_amdgcn_s_setprio(0);
    // ---- P2: read B n234; stage Bb(t+1); VM(5) forces Ap2(t); barrier
#pragma unroll
    for (int n = 2; n < 5; ++n) {
      bfr[n][0] = *(const bf16x8*)&Bb_[(rb + n * 16) * 64 + x0];
      bfr[n][1] = *(const bf16x8*)&Bb_[(rb + n * 16) * 64 + x1];
    }
    if (st) stBb(t + 1);
    LGK0(); SB0();
    __builtin_amdgcn_s_setprio(1);
#pragma unroll
    for (int kk = 0; kk < 2; ++kk)
#pragma unroll
      for (int m = 0; m < 2; ++m)
#pragma unroll
        for (int n = 2; n < 5; ++n)
          acc[m][n] = mfma16(af[m][kk], bfr[n][kk], acc[m][n]);
    __builtin_amdgcn_s_setprio(0);
    if (st) { VMW(5); } else { VMW(0); }
    __builtin_amdgcn_s_barrier();
    SB0();
    // ---- P3: read A m23; stage Ap1(t+1)
#pragma unroll
    for (int m = 0; m < 2; ++m) {
      af[m][0] = *(const bf16x8*)&Ab[(ra + 32 + m * 16) * 64 + x0];
      af[m][1] = *(const bf16x8*)&Ab[(ra + 32 + m * 16) * 64 + x1];
    }
    if (st) stApart(t + 1, 0);
    LGK0(); SB0();
    __builtin_amdgcn_s_setprio(1);
#pragma unroll
    for (int kk = 0; kk < 2; ++kk)
#pragma unroll
      for (int m = 0; m < 2; ++m)
#pragma unroll
        for (int n = 0; n < 2; ++n)
          acc[2 + m][n] = mfma16(af[m][kk], bfr[n][kk], acc[2 + m][n]);
    __builtin_amdgcn_s_setprio(0);
    // ---- P4: stage Ap2(t+1); VM(2) forces Ba/Bb/Ap1(t+1); barrier
    if (st) stApart(t + 1, 1);
    __builtin_amdgcn_s_setprio(1);
#pragma unroll
    for (int kk = 0; kk < 2; ++kk)
#pragma unroll
      for (int m = 0; m < 2; ++m)
#pragma unroll
        for (int n = 2; n < 5; ++n)
          acc[2 + m][n] = mfma16(af[m][kk], bfr[n][kk], acc[2 + m][n]);
    __builtin_amdgcn_s_setprio(0);
    VMW(2);
    __builtin_amdgcn_s_barrier();
    SB0();
  }

#pragma unroll
  for (int m2 = 0; m2 < 4; ++m2)
#pragma unroll
    for (int n = 0; n < 5; ++n) {
      int col = n0 + wc * 80 + n * 16 + l15;
      float bias = (col < 4096) ? pb0[col] : (col < 4608) ? pb1[col - 4096] : pb2[col - 4608];
#pragma unroll
      for (int q = 0; q < 4; ++q) {
        int row = m0 + wr * 64 + m2 * 16 + lg * 4 + q;
        Cout[(size_t)row * LDC + col] = f2bf(acc[m2][n][q] + bias);
      }
    }
}

// =================================================================
// Out-proj GEMM: 128M x 96N tiles -> grid 16x30 = 480 blocks (~2/CU)
// =================================================================
__global__ __launch_bounds__(256, 2) void k_gemmo(
    const u16* __restrict__ A, const u16* __restrict__ Bgl, float* __restrict__ Cout,
    const float* __restrict__ pb0)
{
  constexpr int K = 4096, NT = 64, LDC = 2880;
  __shared__ u16 Asm[2][128 * 64];
  __shared__ u16 Bsm[2][96 * 64];

  const int bid = blockIdx.x;
  const int swz = (bid & 7) * 60 + (bid >> 3);   // 480 % 8 == 0, bijective
  const int bx = swz / 16, by = swz & 15;
  const int m0 = by * 128, n0 = bx * 96;

  const int tid = threadIdx.x;
  const int w = tid >> 6, lane = tid & 63;
  const int l15 = lane & 15, lg = lane >> 4;
  const int wr = w >> 1, wc = w & 1;

  const u16* Ag = A + (size_t)m0 * K;
  const u16* Bg = Bgl + (size_t)n0 * K;

  auto ld1 = [&](const u16* s, u16* d, int slot) {
    int row = slot >> 3, c = slot & 7;
    gl_lds16(s + (size_t)row * K + ((c ^ (row & 7)) << 3), d + row * 64 + c * 8);
  };
  auto stApart = [&](int tg, int part) {
    u16* d = Asm[tg & 1];
    const u16* s = Ag + tg * 64;
    ld1(s, d, part * 256 + tid);
    ld1(s, d, part * 256 + 512 + tid);
  };
  auto stB = [&](int tg) {
    u16* d = Bsm[tg & 1];
    const u16* s = Bg + tg * 64;
    ld1(s, d, tid);
    ld1(s, d, 256 + tid);
    ld1(s, d, 512 + tid);
  };

  const int ra = wr * 64 + l15;
  const int rb = wc * 48 + l15;
  const int x0 = (lg ^ (l15 & 7)) << 3;
  const int x1 = x0 ^ 32;

  f32x4 acc[4][3] = {};
  bf16x8 af[2][2], bfr[3][2];

  stB(0); stApart(0, 0); stApart(0, 1);
  VMW(2);
  __builtin_amdgcn_s_barrier();
  SB0();

  for (int t = 0; t < NT; ++t) {
    const u16* Ab = Asm[t & 1];
    const u16* Bb_ = Bsm[t & 1];
    const bool st = (t + 1 < NT);
    // ---- P1
#pragma unroll
    for (int m = 0; m < 2; ++m) {
      af[m][0] = *(const bf16x8*)&Ab[(ra + m * 16) * 64 + x0];
      af[m][1] = *(const bf16x8*)&Ab[(ra + m * 16) * 64 + x1];
    }
#pragma unroll
    for (int n = 0; n < 3; ++n) {
      bfr[n][0] = *(const bf16x8*)&Bb_[(rb + n * 16) * 64 + x0];
      bfr[n][1] = *(const bf16x8*)&Bb_[(rb + n * 16) * 64 + x1];
    }
    if (st) { stB(t + 1); stApart(t + 1, 0); }
    LGK0(); SB0();
    __builtin_amdgcn_s_setprio(1);
#pragma unroll
    for (int kk = 0; kk < 2; ++kk)
#pragma unroll
      for (int m = 0; m < 2; ++m)
#pragma unroll
        for (int n = 0; n < 3; ++n)
          acc[m][n] = mfma16(af[m][kk], bfr[n][kk], acc[m][n]);
    __builtin_amdgcn_s_setprio(0);
    if (st) { VMW(5); } else { VMW(0); }
    __builtin_amdgcn_s_barrier();
    SB0();
    // ---- P2
#pragma unroll
    for (int m = 0; m < 2; ++m) {
      af[m][0] = *(const bf16x8*)&Ab[(ra + 32 + m * 16) * 64 + x0];
      af[m][1] = *(const bf16x8*)&Ab[(ra + 32 + m * 16) * 64 + x1];
    }
    if (st) stApart(t + 1, 1);
    LGK0(); SB0();
    __builtin_amdgcn_s_setprio(1);
#pragma unroll
    for (int kk = 0; kk < 2; ++kk)
#pragma unroll
      for (int m = 0; m < 2; ++m)
#pragma unroll
        for (int n = 0; n < 3; ++n)
          acc[2 + m][n] = mfma16(af[m][kk], bfr[n][kk], acc[2 + m][n]);
    __builtin_amdgcn_s_setprio(0);
    VMW(2);
    __builtin_amdgcn_s_barrier();
    SB0();
  }

#pragma unroll
  for (int m2 = 0; m2 < 4; ++m2)
#pragma unroll
    for (int n = 0; n < 3; ++n) {
      int col = n0 + wc * 48 + n * 16 + l15;
      float bias = pb0[col];
#pragma unroll
      for (int q = 0; q < 4; ++q) {
        int row = m0 + wr * 64 + m2 * 16 + lg * 4 + q;
        Cout[(size_t)row * LDC + col] = acc[m2][n][q] + bias;
      }
    }
}

// ---------------- in-place RoPE on QKV cols [0, 4608) ----------------
__global__ void k_rope(u16* __restrict__ qkv, const float* __restrict__ cosb,
                       const float* __restrict__ sinb) {
  int idx = blockIdx.x * 256 + threadIdx.x;
  if (idx >= 2048 * 72 * 4) return;
  int oct = idx & 3;
  int h = (idx >> 2) % 72;
  int s = idx / 288;
  u16* p1 = qkv + (size_t)s * 5120 + h * 64 + oct * 8;
  u16* p2 = p1 + 32;
  const float* pc = cosb + (size_t)s * 64 + oct * 8;
  const float* ps = sinb + (size_t)s * 64 + oct * 8;
  u32x4 a = *(const u32x4*)p1;
  u32x4 b = *(const u32x4*)p2;
  f32x4 c0 = *(const f32x4*)pc, c1 = *(const f32x4*)(pc + 4);
  f32x4 s0 = *(const f32x4*)ps, s1 = *(const f32x4*)(ps + 4);
  float C[8] = {c0[0], c0[1], c0[2], c0[3], c1[0], c1[1], c1[2], c1[3]};
  float Sn[8] = {s0[0], s0[1], s0[2], s0[3], s1[0], s1[1], s1[2], s1[3]};
  u32x4 ra, rb;
#pragma unroll
  for (int i = 0; i < 4; ++i) {
    float x1l = bflo(a[i]), x1h = bfhi(a[i]);
    float x2l = bflo(b[i]), x2h = bfhi(b[i]);
    float o1l = x1l * C[2 * i] - x2l * Sn[2 * i];
    float o1h = x1h * C[2 * i + 1] - x2h * Sn[2 * i + 1];
    float o2l = x2l * C[2 * i] + x1l * Sn[2 * i];
    float o2h = x2h * C[2 * i + 1] + x1h * Sn[2 * i + 1];
    ra[i] = (u32)f2bf(o1l) | ((u32)f2bf(o1h) << 16);
    rb[i] = (u32)f2bf(o2l) | ((u32)f2bf(o2h) << 16);
  }
  *(u32x4*)p1 = ra;
  *(u32x4*)p2 = rb;
}

// ---------------- sliding-window GQA attention with sinks ----------------
// grid (S/64, NKV); block 512 = 8 waves = 8 q-heads. Each wave does two
// 32-q subtiles sequentially against one shared 192-row K/V window.
__global__ __launch_bounds__(512, 1) void k_attn(
    const u16* __restrict__ qkv, const float* __restrict__ sinks, u16* __restrict__ aout)
{
  __shared__ u16 Kl[192 * 64];
  __shared__ u16 Vt[64 * 200];
  __shared__ u16 Pl[8][2][16][40];

  const int qt = blockIdx.x * 64;
  const int kv = blockIdx.y;
  const int tid = threadIdx.x;
  const int w = tid >> 6, lane = tid & 63;
  const int l15 = lane & 15, lg = lane >> 4;

  for (int idx = tid; idx < 192 * 8; idx += 512) {
    int row = idx >> 3, ch = idx & 7;
    int key = qt - 128 + row;
    u32x4 val = {0, 0, 0, 0};
    if (key >= 0) val = *(const u32x4*)(qkv + (size_t)key * 5120 + 4096 + kv * 64 + ch * 8);
    *(u32x4*)((char*)Kl + row * 128 + ((ch * 16) ^ ((row & 7) << 4))) = val;
  }
  for (int idx = tid; idx < 192 * 8; idx += 512) {
    int row = idx >> 3, ch = idx & 7;
    int key = qt - 128 + row;
    u32x4 val = {0, 0, 0, 0};
    if (key >= 0) val = *(const u32x4*)(qkv + (size_t)key * 5120 + 4608 + kv * 64 + ch * 8);
    const u16* pv16 = (const u16*)&val;
#pragma unroll
    for (int j = 0; j < 8; ++j) Vt[(ch * 8 + j) * 200 + row] = pv16[j];
  }
  __syncthreads();

  const int h = kv * 8 + w;
  const float sink = sinks[h];

  for (int qs = 0; qs < 2; ++qs) {
    const int qb = qt + qs * 32;
    bf16x8 qf[2][2];
#pragma unroll
    for (int rt = 0; rt < 2; ++rt)
#pragma unroll
      for (int ks = 0; ks < 2; ++ks)
        qf[rt][ks] = *(const bf16x8*)(qkv + (size_t)(qb + rt * 16 + l15) * 5120 + h * 64 + ks * 32 + lg * 8);

    f32x4 S[2][5][2];
#pragma unroll
    for (int kb = 0; kb < 5; ++kb)
#pragma unroll
      for (int hh = 0; hh < 2; ++hh) {
        int krow = qs * 32 + kb * 32 + hh * 16 + l15;
        int sw = (krow & 7) << 4;
        bf16x8 kf0 = *(const bf16x8*)((const char*)Kl + krow * 128 + ((lg * 16) ^ sw));
        bf16x8 kf1 = *(const bf16x8*)((const char*)Kl + krow * 128 + ((64 + lg * 16) ^ sw));
#pragma unroll
        for (int rt = 0; rt < 2; ++rt) {
          f32x4 a = {0.f, 0.f, 0.f, 0.f};
          a = mfma16(qf[rt][0], kf0, a);
          a = mfma16(qf[rt][1], kf1, a);
          S[rt][kb][hh] = a;
        }
      }

    float inv_s[2][4];
#pragma unroll
    for (int rt = 0; rt < 2; ++rt)
#pragma unroll
      for (int r = 0; r < 4; ++r) {
        int q_abs = qb + rt * 16 + lg * 4 + r;
        float m = -1e30f;
#pragma unroll
        for (int kb = 0; kb < 5; ++kb)
#pragma unroll
          for (int hh = 0; hh < 2; ++hh) {
            int k_abs = qb - 128 + kb * 32 + hh * 16 + l15;
            float v = S[rt][kb][hh][r] * 0.125f;
            bool ok = (k_abs >= 0) && (k_abs <= q_abs) && (q_abs - k_abs < 128);
            v = ok ? v : -1e30f;
            S[rt][kb][hh][r] = v;
            m = fmaxf(m, v);
          }
        m = fmaxf(m, __shfl_xor(m, 1, 64));
        m = fmaxf(m, __shfl_xor(m, 2, 64));
        m = fmaxf(m, __shfl_xor(m, 4, 64));
        m = fmaxf(m, __shfl_xor(m, 8, 64));
        m = fmaxf(m, sink);
        float sum = 0.f;
#pragma unroll
        for (int kb = 0; kb < 5; ++kb)
#pragma unroll
          for (int hh = 0; hh < 2; ++hh) {
            float p = __expf(S[rt][kb][hh][r] - m);
            S[rt][kb][hh][r] = p;
            sum += p;
          }
        sum += __shfl_xor(sum, 1, 64);
        sum += __shfl_xor(sum, 2, 64);
        sum += __shfl_xor(sum, 4, 64);
        sum += __shfl_xor(sum, 8, 64);
        inv_s[rt][r] = 1.0f / (sum + __expf(sink - m));
      }

    f32x4 pv[2][4] = {};
#pragma unroll
    for (int kb = 0; kb < 5; ++kb) {
      asm volatile("s_waitcnt lgkmcnt(0)" ::: "memory");
#pragma unroll
      for (int rt = 0; rt < 2; ++rt)
#pragma unroll
        for (int hh = 0; hh < 2; ++hh)
#pragma unroll
          for (int r = 0; r < 4; ++r)
            Pl[w][rt][lg * 4 + r][hh * 16 + l15] = f2bf(S[rt][kb][hh][r] * inv_s[rt][r]);
      asm volatile("s_waitcnt lgkmcnt(0)" ::: "memory");
      __builtin_amdgcn_sched_barrier(0);
      bf16x8 a0 = *(const bf16x8*)&Pl[w][0][l15][lg * 8];
      bf16x8 a1 = *(const bf16x8*)&Pl[w][1][l15][lg * 8];
#pragma unroll
      for (int nt = 0; nt < 4; ++nt) {
        bf16x8 vf = *(const bf16x8*)&Vt[(nt * 16 + l15) * 200 + qs * 32 + kb * 32 + lg * 8];
        pv[0][nt] = mfma16(a0, vf, pv[0][nt]);
        pv[1][nt] = mfma16(a1, vf, pv[1][nt]);
      }
    }

#pragma unroll
    for (int rt = 0; rt < 2; ++rt)
#pragma unroll
      for (int nt = 0; nt < 4; ++nt)
#pragma unroll
        for (int r = 0; r < 4; ++r)
          aout[(size_t)(qb + rt * 16 + lg * 4 + r) * 4096 + h * 64 + nt * 16 + l15] =
              f2bf(pv[rt][nt][r]);
  }
}

extern "C" void kernel_launch(void* const* d_in, const int* in_sizes, int n_in,
                              void* d_out, int out_size, void* d_ws, size_t ws_size,
                              hipStream_t stream) {
  const float* hs    = (const float*)d_in[0];
  const float* cosb  = (const float*)d_in[1];
  const float* sinb  = (const float*)d_in[2];
  const float* Wq    = (const float*)d_in[3];
  const float* bq    = (const float*)d_in[4];
  const float* Wk    = (const float*)d_in[5];
  const float* bk    = (const float*)d_in[6];
  const float* Wv    = (const float*)d_in[7];
  const float* bv    = (const float*)d_in[8];
  const float* Wo    = (const float*)d_in[9];
  const float* bo    = (const float*)d_in[10];
  const float* sinks = (const float*)d_in[11];

  char* ws = (char*)d_ws;
  u16* hsb   = (u16*)ws;  ws += (size_t)2048 * 2880 * 2;
  u16* WqkvT = (u16*)ws;  ws += (size_t)5120 * 2880 * 2;
  u16* WoT   = (u16*)ws;  ws += (size_t)2880 * 4096 * 2;
  u16* QKV   = (u16*)ws;  ws += (size_t)2048 * 5120 * 2;
  u16* AOut  = (u16*)ws;  ws += (size_t)2048 * 4096 * 2;

  k_cvt<<<5760, 256, 0, stream>>>(hs, hsb, 1474560);
  k_tcvt2<<<dim3(4096 / 64, 2880 / 64), 256, 0, stream>>>(Wq, WqkvT, 2880, 4096);
  k_tcvt2<<<dim3(512 / 64, 2880 / 64), 256, 0, stream>>>(Wk, WqkvT + (size_t)4096 * 2880, 2880, 512);
  k_tcvt2<<<dim3(512 / 64, 2880 / 64), 256, 0, stream>>>(Wv, WqkvT + (size_t)4608 * 2880, 2880, 512);
  k_tcvt2<<<dim3(2880 / 64, 4096 / 64), 256, 0, stream>>>(Wo, WoT, 4096, 2880);

  k_gemmq<<<512, 256, 0, stream>>>(hsb, WqkvT, QKV, bq, bk, bv);

  k_rope<<<2304, 256, 0, stream>>>(QKV, cosb, sinb);

  k_attn<<<dim3(32, 8), 512, 0, stream>>>(QKV, sinks, AOut);

  k_gemmo<<<480, 256, 0, stream>>>(AOut, WoT, (float*)d_out, bo);
}